// Round 1
// baseline (406.347 us; speedup 1.0000x reference)
//
#include <hip/hip_runtime.h>

typedef unsigned short u16;
typedef __attribute__((ext_vector_type(4))) unsigned int u32x4;
typedef __attribute__((ext_vector_type(4))) float f32x4;
typedef __attribute__((ext_vector_type(8))) short s16x8;

#define B_ 8
#define T_ 2048
#define C_ 1024
#define H_ 16
#define HS_ 64
#define CHUNK_ 256
#define NC_ 8

union U8 { u32x4 u; u16 h[8]; };

__device__ __forceinline__ float b2f(u16 v) {
    union { unsigned int i; float f; } c; c.i = ((unsigned int)v) << 16; return c.f;
}
__device__ __forceinline__ u16 f2b(float f) {
    union { float f; unsigned int i; } c; c.f = f;
    unsigned int i = c.i;
    return (u16)((i + 0x7FFFu + ((i >> 16) & 1u)) >> 16);  // RNE
}
// fast sigmoid: v_exp_f32 + v_rcp_f32 (args here are tiny, ~0.02 — no range issues)
__device__ __forceinline__ float fsig(float z) {
    return __builtin_amdgcn_rcpf(1.f + __expf(-z));
}

// async 16B global->LDS (lds dest = wave-uniform base + lane*16)
typedef __attribute__((address_space(1))) void GV;
typedef __attribute__((address_space(3))) void LV;
__device__ __forceinline__ void glds16(const void* g, void* l) {
    __builtin_amdgcn_global_load_lds((GV*)g, (LV*)l, 16, 0, 0);
}

// ---------------- K0: f32 -> bf16 conversion of the 4 weight matrices ------
__global__ __launch_bounds__(256) void cvt4_kernel(
    const float* __restrict__ s0, const float* __restrict__ s1,
    const float* __restrict__ s2, const float* __restrict__ s3,
    u16* __restrict__ dst)
{
    int i = blockIdx.x * 256 + threadIdx.x;   // 4 * 131072 threads, 8 elems each
    int m = i >> 17;
    const float* s = (m == 0) ? s0 : (m == 1) ? s1 : (m == 2) ? s2 : s3;
    size_t j = (size_t)(i & 131071) * 8;
    f32x4 a = *reinterpret_cast<const f32x4*>(s + j);
    f32x4 b = *reinterpret_cast<const f32x4*>(s + j + 4);
    U8 o;
    #pragma unroll
    for (int k = 0; k < 4; k++) { o.h[k] = f2b(a[k]); o.h[4 + k] = f2b(b[k]); }
    *reinterpret_cast<u32x4*>(dst + (size_t)m * C_ * C_ + j) = o.u;
}

// ---------------- K1: gate + time-shift + maa mix, 8-row t-strip ------------
__global__ __launch_bounds__(256) void mix_kernel(
    const float* __restrict__ x, const float* __restrict__ vol,
    const float* __restrict__ Wvol, const float* __restrict__ bvol,
    const float* __restrict__ mk, const float* __restrict__ mv, const float* __restrict__ mr,
    u16* __restrict__ xk, u16* __restrict__ xv, u16* __restrict__ xr)
{
    int idx = blockIdx.x * 256 + threadIdx.x;      // B*(T/8)*(C/8) threads
    int c0 = (idx & 127) * 8;
    int bt8 = idx >> 7;
    int t0  = (bt8 & 255) * 8;
    int b   = bt8 >> 8;
    size_t rowOff = ((size_t)b * T_ + t0) * C_ + c0;

    float wv[8], bv[8], mkv[8], mvv[8], mrv[8];
    #pragma unroll
    for (int j = 0; j < 8; j += 4) {
        f32x4 a;
        a = *reinterpret_cast<const f32x4*>(Wvol + c0 + j);
        wv[j] = a[0]; wv[j+1] = a[1]; wv[j+2] = a[2]; wv[j+3] = a[3];
        a = *reinterpret_cast<const f32x4*>(bvol + c0 + j);
        bv[j] = a[0]; bv[j+1] = a[1]; bv[j+2] = a[2]; bv[j+3] = a[3];
        a = *reinterpret_cast<const f32x4*>(mk + c0 + j);
        mkv[j] = a[0]; mkv[j+1] = a[1]; mkv[j+2] = a[2]; mkv[j+3] = a[3];
        a = *reinterpret_cast<const f32x4*>(mv + c0 + j);
        mvv[j] = a[0]; mvv[j+1] = a[1]; mvv[j+2] = a[2]; mvv[j+3] = a[3];
        a = *reinterpret_cast<const f32x4*>(mr + c0 + j);
        mrv[j] = a[0]; mrv[j+1] = a[1]; mrv[j+2] = a[2]; mrv[j+3] = a[3];
    }

    const float* volb = vol + (size_t)b * T_;
    float gp[8];
    if (t0 == 0) {
        #pragma unroll
        for (int j = 0; j < 8; j++) gp[j] = 0.f;
    } else {
        float vp = volb[t0 - 1];
        #pragma unroll
        for (int j = 0; j < 8; j += 4) {
            f32x4 a = *reinterpret_cast<const f32x4*>(x + rowOff - C_ + j);
            gp[j]   = a[0] * fsig(vp * wv[j]   + bv[j]);
            gp[j+1] = a[1] * fsig(vp * wv[j+1] + bv[j+1]);
            gp[j+2] = a[2] * fsig(vp * wv[j+2] + bv[j+2]);
            gp[j+3] = a[3] * fsig(vp * wv[j+3] + bv[j+3]);
        }
    }

    #pragma unroll
    for (int s = 0; s < 8; s++) {
        float vc = volb[t0 + s];
        size_t off = rowOff + (size_t)s * C_;
        float g[8];
        #pragma unroll
        for (int j = 0; j < 8; j += 4) {
            f32x4 a = *reinterpret_cast<const f32x4*>(x + off + j);
            g[j]   = a[0] * fsig(vc * wv[j]   + bv[j]);
            g[j+1] = a[1] * fsig(vc * wv[j+1] + bv[j+1]);
            g[j+2] = a[2] * fsig(vc * wv[j+2] + bv[j+2]);
            g[j+3] = a[3] * fsig(vc * wv[j+3] + bv[j+3]);
        }
        U8 ok, ov, orr;
        #pragma unroll
        for (int j = 0; j < 8; j++) {
            float xx = gp[j] - g[j];
            ok.h[j]  = f2b(g[j] + xx * mkv[j]);
            ov.h[j]  = f2b(g[j] + xx * mvv[j]);
            orr.h[j] = f2b(g[j] + xx * mrv[j]);
            gp[j] = g[j];
        }
        *reinterpret_cast<u32x4*>(xk + off) = ok.u;
        *reinterpret_cast<u32x4*>(xv + off) = ov.u;
        *reinterpret_cast<u32x4*>(xr + off) = orr.u;
    }
}

// ---------------- K2: C = A @ W^T -------------------------------------------
// 256x128 tile, BK=64, 4 waves (each 128x64 out), ring-3 LDS, 3-deep
// prefetch with counted vmcnt(12), ONE raw s_barrier per K-tile (no vmcnt(0)
// drain in steady state). bf16 output staged through LDS for full-line writes.
#define GBM_ 256
#define GBN_ 128
#define GBK_ 64
#define GEMM_LDS_BYTES (3 * (GBM_ * GBK_ + GBN_ * GBK_) * 2)  // 147456

template<bool F32OUT>
__global__ __launch_bounds__(256) void gemm_bt(
    const u16* __restrict__ A, const u16* __restrict__ W,
    void* __restrict__ Cc, int M, int N, int K)
{
    extern __shared__ __align__(16) u16 lds[];
    u16* As = lds;                       // 3 slots of 256*64 u16
    u16* Bs = lds + 3 * (GBM_ * GBK_);   // 3 slots of 128*64 u16
    const int tid  = threadIdx.x;
    const int lane = tid & 63, wave = tid >> 6;
    const int r16  = lane & 15, quad = lane >> 4;
    const int wm = (wave >> 1) * 128;    // wave's M offset in tile
    const int wn = (wave & 1) * 64;      // wave's N offset in tile
    const int bm = blockIdx.x, bn = blockIdx.y;
    const int NT = K >> 6;

    const u16* Ab = A + (size_t)bm * GBM_ * K;
    const u16* Wb = W + (size_t)bn * GBN_ * K;

    // staging geometry: chunk p = (i*4+wave)*64 + lane; row=p>>3, col-chunk
    // swizzled on the GLOBAL side so LDS stays linear (glds requirement).
    const int ln3 = lane >> 3;                   // row & 7
    const int csw = ((lane & 7) ^ ln3) * 8;      // pre-swizzled k-chunk (elems)

    f32x4 acc[8][4];
    #pragma unroll
    for (int mi = 0; mi < 8; mi++)
        #pragma unroll
        for (int ni = 0; ni < 4; ni++)
            acc[mi][ni] = f32x4{0.f, 0.f, 0.f, 0.f};

    // fragment read bases (chunk XOR uses r16&7 == row&7)
    const int fA0 = (wm + r16) * GBK_;
    const int fB0 = (wn + r16) * GBK_;
    const int kc0 = quad ^ (r16 & 7);            // k-chunk for ks=0; ^4 for ks=1

#define STAGE(tt) {                                                          \
    const int k0_ = (tt) << 6; const int sl_ = (tt) % 3;                     \
    u16* Asl_ = As + sl_ * (GBM_ * GBK_);                                    \
    u16* Bsl_ = Bs + sl_ * (GBN_ * GBK_);                                    \
    _Pragma("unroll")                                                        \
    for (int i = 0; i < 8; i++)                                              \
        glds16(Ab + k0_ + (size_t)((i * 4 + wave) * 8 + ln3) * K + csw,      \
               Asl_ + (i * 4 + wave) * 512);                                 \
    _Pragma("unroll")                                                        \
    for (int i = 0; i < 4; i++)                                              \
        glds16(Wb + k0_ + (size_t)((i * 4 + wave) * 8 + ln3) * K + csw,      \
               Bsl_ + (i * 4 + wave) * 512);                                 \
}

    STAGE(0);
    STAGE(1);

    for (int t = 0; t < NT; ++t) {
        // own-wave wait BEFORE barrier => after barrier ALL waves' tile-t
        // loads have landed. 12 = loads of the one newer tile in flight.
        if (t < NT - 1) asm volatile("s_waitcnt vmcnt(12)" ::: "memory");
        else            asm volatile("s_waitcnt vmcnt(0)"  ::: "memory");
        __builtin_amdgcn_s_barrier();
        asm volatile("" ::: "memory");
        __builtin_amdgcn_sched_barrier(0);

        // stage t+2 into slot (t-1)%3: its reads finished before this barrier
        if (t + 2 < NT) STAGE(t + 2);

        const u16* At = As + (t % 3) * (GBM_ * GBK_);
        const u16* Bt = Bs + (t % 3) * (GBN_ * GBK_);
        #pragma unroll
        for (int ks = 0; ks < 2; ks++) {
            const int co = (kc0 ^ (ks * 4)) * 8;
            s16x8 fb[4];
            #pragma unroll
            for (int ni = 0; ni < 4; ni++)
                fb[ni] = *reinterpret_cast<const s16x8*>(Bt + fB0 + ni * 1024 + co);
            #pragma unroll
            for (int mi = 0; mi < 8; mi++) {
                s16x8 fa = *reinterpret_cast<const s16x8*>(At + fA0 + mi * 1024 + co);
                #pragma unroll
                for (int ni = 0; ni < 4; ni++)
                    acc[mi][ni] = __builtin_amdgcn_mfma_f32_16x16x32_bf16(
                        fa, fb[ni], acc[mi][ni], 0, 0, 0);
            }
        }
    }
#undef STAGE

    __builtin_amdgcn_s_barrier();   // protect ring slots before LDS reuse
    asm volatile("" ::: "memory");

    if constexpr (F32OUT) {
        // f32 stores: 16 lanes * 4B = 64B full lines already — direct store
        float* C = (float*)Cc;
        #pragma unroll
        for (int mi = 0; mi < 8; mi++) {
            int row0 = bm * GBM_ + wm + mi * 16 + quad * 4;
            #pragma unroll
            for (int ni = 0; ni < 4; ni++) {
                int col = bn * GBN_ + wn + ni * 16 + r16;
                #pragma unroll
                for (int i = 0; i < 4; i++)
                    C[(size_t)(row0 + i) * N + col] = acc[mi][ni][i];
            }
        }
    } else {
        // bf16: stage through LDS (pitch 136) -> 256B-per-row dwordx4 stores
        u16* ep = lds;   // [256][136] u16 = 69632 B, fits in ring area
        #pragma unroll
        for (int mi = 0; mi < 8; mi++)
            #pragma unroll
            for (int ni = 0; ni < 4; ni++)
                #pragma unroll
                for (int i = 0; i < 4; i++)
                    ep[(wm + mi * 16 + quad * 4 + i) * 136 + wn + ni * 16 + r16] =
                        f2b(acc[mi][ni][i]);
        __syncthreads();
        u16* C = (u16*)Cc;
        int seg = tid & 15, rr = tid >> 4;
        #pragma unroll
        for (int it = 0; it < 16; it++) {
            int row = it * 16 + rr;
            u32x4 val = *reinterpret_cast<const u32x4*>(ep + row * 136 + seg * 8);
            *reinterpret_cast<u32x4*>(C + (size_t)(bm * GBM_ + row) * N + bn * GBN_ + seg * 8) = val;
        }
    }
}

// ---------------- K3a: P = v^T k per (b,h,chunk) via MFMA -------------------
__global__ __launch_bounds__(256) void kvouter_kernel(
    const u16* __restrict__ k, const u16* __restrict__ v, float* __restrict__ S)
{
    int blk = blockIdx.x;          // bh*NC + j
    int j  = blk & (NC_ - 1);
    int bh = blk >> 3;
    int h = bh & (H_ - 1);
    int b = bh >> 4;
    __shared__ __align__(16) u16 kT[HS_ * 136];
    __shared__ __align__(16) u16 vT[HS_ * 136];
    int tid = threadIdx.x, lane = tid & 63, wave = tid >> 6;
    int r16 = lane & 15, quad = lane >> 4;
    int n0 = (wave >> 1) * 32, m0 = (wave & 1) * 32;
    int a = tid & 7, c8 = a * 8;

    f32x4 acc[2][2];
    #pragma unroll
    for (int ni = 0; ni < 2; ni++)
        #pragma unroll
        for (int mi = 0; mi < 2; mi++)
            acc[ni][mi] = f32x4{0.f, 0.f, 0.f, 0.f};

    size_t base = ((size_t)(b * T_ + j * CHUNK_)) * C_ + h * HS_;
    #pragma unroll
    for (int half = 0; half < 2; half++) {
        size_t hb = base + (size_t)half * 128 * C_;
        #pragma unroll
        for (int i = 0; i < 4; i++) {
            int s = (tid + i * 256) >> 3;
            U8 uk, uv;
            uk.u = *reinterpret_cast<const u32x4*>(k + hb + (size_t)s * C_ + c8);
            uv.u = *reinterpret_cast<const u32x4*>(v + hb + (size_t)s * C_ + c8);
            #pragma unroll
            for (int jj = 0; jj < 8; jj++) {
                int w = jj ^ a;
                kT[(c8 + w) * 136 + s] = uk.h[w];
                vT[(c8 + w) * 136 + s] = uv.h[w];
            }
        }
        __syncthreads();
        #pragma unroll
        for (int ks = 0; ks < 4; ks++) {
            s16x8 fa[2], fb[2];
            #pragma unroll
            for (int ni = 0; ni < 2; ni++)
                fa[ni] = *reinterpret_cast<const s16x8*>(
                    &vT[(n0 + ni * 16 + r16) * 136 + ks * 32 + quad * 8]);
            #pragma unroll
            for (int mi = 0; mi < 2; mi++)
                fb[mi] = *reinterpret_cast<const s16x8*>(
                    &kT[(m0 + mi * 16 + r16) * 136 + ks * 32 + quad * 8]);
            #pragma unroll
            for (int ni = 0; ni < 2; ni++)
                #pragma unroll
                for (int mi = 0; mi < 2; mi++)
                    acc[ni][mi] = __builtin_amdgcn_mfma_f32_16x16x32_bf16(fa[ni], fb[mi], acc[ni][mi], 0, 0, 0);
        }
        __syncthreads();
    }
    float* out = S + (size_t)blk * (HS_ * HS_);
    #pragma unroll
    for (int ni = 0; ni < 2; ni++)
        #pragma unroll
        for (int mi = 0; mi < 2; mi++)
            #pragma unroll
            for (int i = 0; i < 4; i++)
                out[(n0 + ni * 16 + quad * 4 + i) * HS_ + m0 + mi * 16 + r16] = acc[ni][mi][i];
}

// ---------------- K3b: decay scan (elementwise in (n,m) layout) -------------
__global__ __launch_bounds__(256) void scan_kernel(
    const float* __restrict__ S, const float* __restrict__ td, u16* __restrict__ stT)
{
    int bh = blockIdx.x;
    int h = bh & (H_ - 1);
    float w = expf(-expf(td[h]));
    int tid = threadIdx.x;
    float st[16];
    #pragma unroll
    for (int i = 0; i < 16; i++) st[i] = 0.f;
    for (int c = 0; c < NC_; c++) {
        size_t off = ((size_t)(bh * NC_ + c)) * 4096 + tid * 16;
        const float* sp = S + off;
        #pragma unroll
        for (int i = 0; i < 16; i++) st[i] = w * (st[i] + sp[i]);
        U8 o0, o1;
        #pragma unroll
        for (int i = 0; i < 8; i++) { o0.h[i] = f2b(st[i]); o1.h[i] = f2b(st[8 + i]); }
        *reinterpret_cast<u32x4*>(stT + off)     = o0.u;
        *reinterpret_cast<u32x4*>(stT + off + 8) = o1.u;
    }
}

// ---------------- K3c: y = r @ state (MFMA), fused GroupNorm ----------------
__global__ __launch_bounds__(256) void rstate_gn_kernel(
    const u16* __restrict__ r, const u16* __restrict__ stT,
    const float* __restrict__ gnw, const float* __restrict__ gnb, u16* __restrict__ ygn)
{
    int blk = blockIdx.x;      // bh*NC + c
    int c  = blk & (NC_ - 1);
    int bh = blk >> 3;
    int h = bh & (H_ - 1);
    int b = bh >> 4;
    __shared__ __align__(16) u16 sT[HS_ * 72];   // pitch 72 u16
    int tid = threadIdx.x, lane = tid & 63, wave = tid >> 6;
    int r16 = lane & 15, quad = lane >> 4;

    const u16* sg = stT + (size_t)blk * (HS_ * HS_);
    for (int i = tid; i < 512; i += 256) {
        int n = i >> 3, c8 = (i & 7) * 8;
        *reinterpret_cast<u32x4*>(&sT[n * 72 + c8]) =
            *reinterpret_cast<const u32x4*>(sg + n * HS_ + c8);
    }
    __syncthreads();

    size_t rowBase = (size_t)(b * T_ + c * CHUNK_ + wave * 64);
    f32x4 acc[4][4];
    #pragma unroll
    for (int mi = 0; mi < 4; mi++)
        #pragma unroll
        for (int ni = 0; ni < 4; ni++)
            acc[mi][ni] = f32x4{0.f, 0.f, 0.f, 0.f};

    #pragma unroll
    for (int ks = 0; ks < 2; ks++) {
        int kb = ks * 32 + quad * 8;
        s16x8 fa[4], fb[4];
        #pragma unroll
        for (int mi = 0; mi < 4; mi++)
            fa[mi] = *reinterpret_cast<const s16x8*>(
                r + (rowBase + mi * 16 + r16) * C_ + h * HS_ + kb);
        #pragma unroll
        for (int ni = 0; ni < 4; ni++)
            fb[ni] = *reinterpret_cast<const s16x8*>(&sT[(ni * 16 + r16) * 72 + kb]);
        #pragma unroll
        for (int mi = 0; mi < 4; mi++)
            #pragma unroll
            for (int ni = 0; ni < 4; ni++)
                acc[mi][ni] = __builtin_amdgcn_mfma_f32_16x16x32_bf16(fa[mi], fb[ni], acc[mi][ni], 0, 0, 0);
    }

    float gwv[4], gbv[4];
    #pragma unroll
    for (int ni = 0; ni < 4; ni++) {
        int col = ni * 16 + r16;
        gwv[ni] = gnw[h * HS_ + col];
        gbv[ni] = gnb[h * HS_ + col];
    }
    #pragma unroll
    for (int mi = 0; mi < 4; mi++) {
        float s1[4], s2[4];
        #pragma unroll
        for (int i = 0; i < 4; i++) {
            float s = 0.f, ss = 0.f;
            #pragma unroll
            for (int ni = 0; ni < 4; ni++) {
                float v = acc[mi][ni][i];
                s += v; ss += v * v;
            }
            s1[i] = s; s2[i] = ss;
        }
        #pragma unroll
        for (int d = 1; d < 16; d <<= 1) {
            #pragma unroll
            for (int i = 0; i < 4; i++) {
                s1[i] += __shfl_xor(s1[i], d);
                s2[i] += __shfl_xor(s2[i], d);
            }
        }
        #pragma unroll
        for (int i = 0; i < 4; i++) {
            float mu = s1[i] * (1.f / 64.f);
            float var = s2[i] * (1.f / 64.f) - mu * mu;
            float sc = rsqrtf(var + 1e-5f);
            size_t ob = (rowBase + mi * 16 + quad * 4 + i) * C_ + h * HS_;
            #pragma unroll
            for (int ni = 0; ni < 4; ni++)
                ygn[ob + ni * 16 + r16] = f2b((acc[mi][ni][i] - mu) * sc * gwv[ni] + gbv[ni]);
        }
    }
}

// ---------------------------------------------------------------------------
extern "C" void kernel_launch(void* const* d_in, const int* in_sizes, int n_in,
                              void* d_out, int out_size, void* d_ws, size_t ws_size,
                              hipStream_t stream) {
    const float* x    = (const float*)d_in[0];
    const float* vol  = (const float*)d_in[1];
    const float* Wvol = (const float*)d_in[2];
    const float* bvol = (const float*)d_in[3];
    const float* mk   = (const float*)d_in[4];
    const float* mv   = (const float*)d_in[5];
    const float* mr   = (const float*)d_in[6];
    const float* td   = (const float*)d_in[7];
    const float* Wk   = (const float*)d_in[8];
    const float* Wv   = (const float*)d_in[9];
    const float* Wr   = (const float*)d_in[10];
    const float* Wo   = (const float*)d_in[11];
    const float* gnw  = (const float*)d_in[12];
    const float* gnb  = (const float*)d_in[13];
    float* out = (float*)d_out;

    // one-time: allow 144 KB dynamic LDS for the GEMM (host-side, capture-safe)
    static bool init_attr = []() {
        hipFuncSetAttribute(reinterpret_cast<const void*>(gemm_bt<false>),
                            hipFuncAttributeMaxDynamicSharedMemorySize, GEMM_LDS_BYTES);
        hipFuncSetAttribute(reinterpret_cast<const void*>(gemm_bt<true>),
                            hipFuncAttributeMaxDynamicSharedMemorySize, GEMM_LDS_BYTES);
        return true;
    }();
    (void)init_attr;

    char* ws = (char*)d_ws;
    const size_t SLOT = (size_t)B_ * T_ * C_ * 2;   // 33,554,432 B
    // s0: xr -> kb -> ygn ; s1: xk -> vb ; s2: xv -> S(f32) + stT(bf16) ; s3: rb
    u16* xr = (u16*)(ws + 0 * SLOT);
    u16* xk = (u16*)(ws + 1 * SLOT);
    u16* xv = (u16*)(ws + 2 * SLOT);
    u16* rb = (u16*)(ws + 3 * SLOT);
    u16* kb = (u16*)(ws + 0 * SLOT);
    u16* vb = (u16*)(ws + 1 * SLOT);
    float* S   = (float*)(ws + 2 * SLOT);                 // 16.8 MB
    u16*   stT = (u16*)  (ws + 2 * SLOT + SLOT / 2);      // 8.4 MB
    u16* ygn = (u16*)(ws + 0 * SLOT);
    u16* wtb = (u16*)(ws + 4 * SLOT);                     // 4 bf16 weight mats
    u16* wrb = wtb;
    u16* wkb = wrb + (size_t)C_ * C_;
    u16* wvb = wkb + (size_t)C_ * C_;
    u16* wob = wvb + (size_t)C_ * C_;

    cvt4_kernel<<<dim3(4 * (C_ * C_ / 8) / 256), dim3(256), 0, stream>>>(Wr, Wk, Wv, Wo, wtb);

    // B*(T/8)*(C/8) threads = 262144 -> 1024 blocks
    mix_kernel<<<dim3(1024), dim3(256), 0, stream>>>(
        x, vol, Wvol, bvol, mk, mv, mr, xk, xv, xr);

    dim3 gg(16384 / GBM_, 1024 / GBN_);  // (64, 8)
    gemm_bt<false><<<gg, 256, GEMM_LDS_BYTES, stream>>>(xr, wrb, rb, 16384, 1024, 1024);
    gemm_bt<false><<<gg, 256, GEMM_LDS_BYTES, stream>>>(xk, wkb, kb, 16384, 1024, 1024);
    gemm_bt<false><<<gg, 256, GEMM_LDS_BYTES, stream>>>(xv, wvb, vb, 16384, 1024, 1024);

    kvouter_kernel<<<dim3(B_ * H_ * NC_), dim3(256), 0, stream>>>(kb, vb, S);
    scan_kernel<<<dim3(B_ * H_), dim3(256), 0, stream>>>(S, td, stT);
    rstate_gn_kernel<<<dim3(B_ * H_ * NC_), dim3(256), 0, stream>>>(rb, stT, gnw, gnb, ygn);

    gemm_bt<true><<<gg, 256, GEMM_LDS_BYTES, stream>>>(ygn, wob, out, 16384, 1024, 1024);
}

// Round 2
// 383.055 us; speedup vs baseline: 1.0608x; 1.0608x over previous
//
#include <hip/hip_runtime.h>

typedef unsigned short u16;
typedef __attribute__((ext_vector_type(4))) unsigned int u32x4;
typedef __attribute__((ext_vector_type(4))) float f32x4;
typedef __attribute__((ext_vector_type(8))) short s16x8;

#define B_ 8
#define T_ 2048
#define C_ 1024
#define H_ 16
#define HS_ 64
#define CHUNK_ 256
#define NC_ 8

union U8 { u32x4 u; u16 h[8]; };

__device__ __forceinline__ float b2f(u16 v) {
    union { unsigned int i; float f; } c; c.i = ((unsigned int)v) << 16; return c.f;
}
__device__ __forceinline__ u16 f2b(float f) {
    union { float f; unsigned int i; } c; c.f = f;
    unsigned int i = c.i;
    return (u16)((i + 0x7FFFu + ((i >> 16) & 1u)) >> 16);  // RNE
}
// fast sigmoid: v_exp_f32 + v_rcp_f32 (args here are tiny, ~0.02 — no range issues)
__device__ __forceinline__ float fsig(float z) {
    return __builtin_amdgcn_rcpf(1.f + __expf(-z));
}

// async 16B global->LDS (lds dest = wave-uniform base + lane*16)
typedef __attribute__((address_space(1))) void GV;
typedef __attribute__((address_space(3))) void LV;
__device__ __forceinline__ void glds16(const void* g, void* l) {
    __builtin_amdgcn_global_load_lds((GV*)g, (LV*)l, 16, 0, 0);
}

// ---------------- K0: f32 -> bf16 conversion of the 4 weight matrices ------
__global__ __launch_bounds__(256) void cvt4_kernel(
    const float* __restrict__ s0, const float* __restrict__ s1,
    const float* __restrict__ s2, const float* __restrict__ s3,
    u16* __restrict__ dst)
{
    int i = blockIdx.x * 256 + threadIdx.x;   // 4 * 131072 threads, 8 elems each
    int m = i >> 17;
    const float* s = (m == 0) ? s0 : (m == 1) ? s1 : (m == 2) ? s2 : s3;
    size_t j = (size_t)(i & 131071) * 8;
    f32x4 a = *reinterpret_cast<const f32x4*>(s + j);
    f32x4 b = *reinterpret_cast<const f32x4*>(s + j + 4);
    U8 o;
    #pragma unroll
    for (int k = 0; k < 4; k++) { o.h[k] = f2b(a[k]); o.h[4 + k] = f2b(b[k]); }
    *reinterpret_cast<u32x4*>(dst + (size_t)m * C_ * C_ + j) = o.u;
}

// ---------------- K1: gate + time-shift + maa mix, 8-row t-strip ------------
__global__ __launch_bounds__(256) void mix_kernel(
    const float* __restrict__ x, const float* __restrict__ vol,
    const float* __restrict__ Wvol, const float* __restrict__ bvol,
    const float* __restrict__ mk, const float* __restrict__ mv, const float* __restrict__ mr,
    u16* __restrict__ xk, u16* __restrict__ xv, u16* __restrict__ xr)
{
    int idx = blockIdx.x * 256 + threadIdx.x;      // B*(T/8)*(C/8) threads
    int c0 = (idx & 127) * 8;
    int bt8 = idx >> 7;
    int t0  = (bt8 & 255) * 8;
    int b   = bt8 >> 8;
    size_t rowOff = ((size_t)b * T_ + t0) * C_ + c0;

    float wv[8], bv[8], mkv[8], mvv[8], mrv[8];
    #pragma unroll
    for (int j = 0; j < 8; j += 4) {
        f32x4 a;
        a = *reinterpret_cast<const f32x4*>(Wvol + c0 + j);
        wv[j] = a[0]; wv[j+1] = a[1]; wv[j+2] = a[2]; wv[j+3] = a[3];
        a = *reinterpret_cast<const f32x4*>(bvol + c0 + j);
        bv[j] = a[0]; bv[j+1] = a[1]; bv[j+2] = a[2]; bv[j+3] = a[3];
        a = *reinterpret_cast<const f32x4*>(mk + c0 + j);
        mkv[j] = a[0]; mkv[j+1] = a[1]; mkv[j+2] = a[2]; mkv[j+3] = a[3];
        a = *reinterpret_cast<const f32x4*>(mv + c0 + j);
        mvv[j] = a[0]; mvv[j+1] = a[1]; mvv[j+2] = a[2]; mvv[j+3] = a[3];
        a = *reinterpret_cast<const f32x4*>(mr + c0 + j);
        mrv[j] = a[0]; mrv[j+1] = a[1]; mrv[j+2] = a[2]; mrv[j+3] = a[3];
    }

    const float* volb = vol + (size_t)b * T_;
    float gp[8];
    if (t0 == 0) {
        #pragma unroll
        for (int j = 0; j < 8; j++) gp[j] = 0.f;
    } else {
        float vp = volb[t0 - 1];
        #pragma unroll
        for (int j = 0; j < 8; j += 4) {
            f32x4 a = *reinterpret_cast<const f32x4*>(x + rowOff - C_ + j);
            gp[j]   = a[0] * fsig(vp * wv[j]   + bv[j]);
            gp[j+1] = a[1] * fsig(vp * wv[j+1] + bv[j+1]);
            gp[j+2] = a[2] * fsig(vp * wv[j+2] + bv[j+2]);
            gp[j+3] = a[3] * fsig(vp * wv[j+3] + bv[j+3]);
        }
    }

    #pragma unroll
    for (int s = 0; s < 8; s++) {
        float vc = volb[t0 + s];
        size_t off = rowOff + (size_t)s * C_;
        float g[8];
        #pragma unroll
        for (int j = 0; j < 8; j += 4) {
            f32x4 a = *reinterpret_cast<const f32x4*>(x + off + j);
            g[j]   = a[0] * fsig(vc * wv[j]   + bv[j]);
            g[j+1] = a[1] * fsig(vc * wv[j+1] + bv[j+1]);
            g[j+2] = a[2] * fsig(vc * wv[j+2] + bv[j+2]);
            g[j+3] = a[3] * fsig(vc * wv[j+3] + bv[j+3]);
        }
        U8 ok, ov, orr;
        #pragma unroll
        for (int j = 0; j < 8; j++) {
            float xx = gp[j] - g[j];
            ok.h[j]  = f2b(g[j] + xx * mkv[j]);
            ov.h[j]  = f2b(g[j] + xx * mvv[j]);
            orr.h[j] = f2b(g[j] + xx * mrv[j]);
            gp[j] = g[j];
        }
        *reinterpret_cast<u32x4*>(xk + off) = ok.u;
        *reinterpret_cast<u32x4*>(xv + off) = ov.u;
        *reinterpret_cast<u32x4*>(xr + off) = orr.u;
    }
}

// ---------------- K2: C = A @ W^T -------------------------------------------
// 256x256 tile, BK=32, 8 waves (2Mx4N, each 128x64 out), 4-slot LDS ring
// (128 KB), grid = 256 blocks = 1/CU, counted vmcnt(4), one raw barrier per
// K-step, setprio around MFMA. Stage lead = 2 steps: slot (s+2)&3 was last
// read at step s-2 (two barriers ago) -> race-free. XCD locality: bm = id&63
// so the 4 bn-blocks sharing an A-panel land on the same XCD (id mod 8).
#define GBM_ 256
#define GBN_ 256
#define GBK_ 32
#define GK_  1024
#define GNT_ 32                    // GK_/GBK_
#define GEMM_LDS_BYTES 131072      // 4 slots * (256*32 A + 256*32 B) * 2B

template<bool F32OUT>
__global__ __launch_bounds__(512, 2) void gemm_bt(
    const u16* __restrict__ A, const u16* __restrict__ W, void* __restrict__ Cc)
{
    extern __shared__ __align__(16) u16 lds[];
    const int tid  = threadIdx.x;
    const int lane = tid & 63, w = tid >> 6;
    const int r16  = lane & 15, quad = lane >> 4;
    const int wm2  = w >> 2;         // 0..1 : M-half (128 rows)
    const int wn4  = w & 3;          // 0..3 : N-quarter (64 cols)
    const int id   = blockIdx.x;
    const int bm   = id & 63, bn = id >> 6;

    const u16* Ab = A + (size_t)bm * GBM_ * GK_;
    const u16* Wb = W + (size_t)bn * GBN_ * GK_;

    // stage source (per-lane, pre-swizzled 16B chunk: chunk ^= (row>>1)&3)
    const int srow   = lane >> 2;                         // 0..15
    const int schunk = ((lane & 3) ^ ((lane >> 3) & 3)) * 8;
    const u16* aS0 = Ab + (size_t)(w * 32 + srow) * GK_ + schunk;
    const u16* aS1 = aS0 + (size_t)16 * GK_;
    const u16* bS0 = Wb + (size_t)(w * 32 + srow) * GK_ + schunk;
    const u16* bS1 = bS0 + (size_t)16 * GK_;
    // LDS dest bases (wave-uniform); +slot*8192 at runtime. B at u16 ofs 32768.
    u16* aD0 = lds + (w * 32) * 32;
    u16* aD1 = aD0 + 16 * 32;
    u16* bD0 = lds + 32768 + (w * 32) * 32;
    u16* bD1 = bD0 + 16 * 32;

    // fragment read offsets (u16 index), swizzle matches stage side
    const int ksw = (quad ^ ((r16 >> 1) & 3)) * 8;
    int aOff[8], bOff[4];
    #pragma unroll
    for (int mi = 0; mi < 8; mi++)
        aOff[mi] = (wm2 * 128 + mi * 16 + r16) * 32 + ksw;
    #pragma unroll
    for (int ni = 0; ni < 4; ni++)
        bOff[ni] = 32768 + (wn4 * 64 + ni * 16 + r16) * 32 + ksw;

    f32x4 acc[8][4];
    #pragma unroll
    for (int mi = 0; mi < 8; mi++)
        #pragma unroll
        for (int ni = 0; ni < 4; ni++)
            acc[mi][ni] = f32x4{0.f, 0.f, 0.f, 0.f};

#define STG(tt) {                                                        \
    const int bo_ = ((tt) & 3) * 8192;                                   \
    const size_t ko_ = (size_t)(tt) * 32;                                \
    glds16(aS0 + ko_, aD0 + bo_);                                        \
    glds16(aS1 + ko_, aD1 + bo_);                                        \
    glds16(bS0 + ko_, bD0 + bo_);                                        \
    glds16(bS1 + ko_, bD1 + bo_);                                        \
}

    STG(0);
    STG(1);
    asm volatile("s_waitcnt vmcnt(4)" ::: "memory");   // slot0 landed
    __builtin_amdgcn_s_barrier();
    asm volatile("" ::: "memory");

    for (int s = 0; s < GNT_; ++s) {
        const int bo = (s & 3) * 8192;
        if (s + 2 < GNT_) STG(s + 2);

        s16x8 fb[4];
        #pragma unroll
        for (int ni = 0; ni < 4; ni++)
            fb[ni] = *reinterpret_cast<const s16x8*>(lds + bo + bOff[ni]);
        __builtin_amdgcn_s_setprio(1);
        #pragma unroll
        for (int mi = 0; mi < 8; mi++) {
            s16x8 fa = *reinterpret_cast<const s16x8*>(lds + bo + aOff[mi]);
            #pragma unroll
            for (int ni = 0; ni < 4; ni++)
                acc[mi][ni] = __builtin_amdgcn_mfma_f32_16x16x32_bf16(
                    fa, fb[ni], acc[mi][ni], 0, 0, 0);
        }
        __builtin_amdgcn_s_setprio(0);

        // ensure next step's slot (staged at s-1) has landed, then barrier
        if (s + 2 < GNT_) asm volatile("s_waitcnt vmcnt(4)" ::: "memory");
        else              asm volatile("s_waitcnt vmcnt(0)" ::: "memory");
        __builtin_amdgcn_s_barrier();
        asm volatile("" ::: "memory");
    }
#undef STG

    if constexpr (F32OUT) {
        // f32: 16 lanes * 4B = 64B full lines — direct store
        float* C = (float*)Cc;
        #pragma unroll
        for (int mi = 0; mi < 8; mi++) {
            int row0 = bm * GBM_ + wm2 * 128 + mi * 16 + quad * 4;
            #pragma unroll
            for (int ni = 0; ni < 4; ni++) {
                int col = bn * GBN_ + wn4 * 64 + ni * 16 + r16;
                #pragma unroll
                for (int i = 0; i < 4; i++)
                    C[(size_t)(row0 + i) * C_ + col] = acc[mi][ni][i];
            }
        }
    } else {
        // bf16: per-wave LDS patch [64][72] -> 128B-per-row dwordx4 stores
        u16* ep = lds + w * 4608;
        u16* C = (u16*)Cc;
        #pragma unroll
        for (int half = 0; half < 2; half++) {
            #pragma unroll
            for (int mi2 = 0; mi2 < 4; mi2++) {
                int mi = half * 4 + mi2;
                #pragma unroll
                for (int ni = 0; ni < 4; ni++)
                    #pragma unroll
                    for (int i = 0; i < 4; i++)
                        ep[(mi2 * 16 + quad * 4 + i) * 72 + ni * 16 + r16] =
                            f2b(acc[mi][ni][i]);
            }
            #pragma unroll
            for (int it = 0; it < 8; it++) {
                int rr = it * 8 + (lane >> 3);
                u32x4 val = *reinterpret_cast<const u32x4*>(ep + rr * 72 + (lane & 7) * 8);
                size_t grow = (size_t)(bm * GBM_ + wm2 * 128 + half * 64 + rr);
                *reinterpret_cast<u32x4*>(
                    C + grow * C_ + bn * GBN_ + wn4 * 64 + (lane & 7) * 8) = val;
            }
        }
    }
}

// ---------------- K3a: P = v^T k per (b,h,chunk) via MFMA -------------------
__global__ __launch_bounds__(256) void kvouter_kernel(
    const u16* __restrict__ k, const u16* __restrict__ v, float* __restrict__ S)
{
    int blk = blockIdx.x;          // bh*NC + j
    int j  = blk & (NC_ - 1);
    int bh = blk >> 3;
    int h = bh & (H_ - 1);
    int b = bh >> 4;
    __shared__ __align__(16) u16 kT[HS_ * 136];
    __shared__ __align__(16) u16 vT[HS_ * 136];
    int tid = threadIdx.x, lane = tid & 63, wave = tid >> 6;
    int r16 = lane & 15, quad = lane >> 4;
    int n0 = (wave >> 1) * 32, m0 = (wave & 1) * 32;
    int a = tid & 7, c8 = a * 8;

    f32x4 acc[2][2];
    #pragma unroll
    for (int ni = 0; ni < 2; ni++)
        #pragma unroll
        for (int mi = 0; mi < 2; mi++)
            acc[ni][mi] = f32x4{0.f, 0.f, 0.f, 0.f};

    size_t base = ((size_t)(b * T_ + j * CHUNK_)) * C_ + h * HS_;
    #pragma unroll
    for (int half = 0; half < 2; half++) {
        size_t hb = base + (size_t)half * 128 * C_;
        #pragma unroll
        for (int i = 0; i < 4; i++) {
            int s = (tid + i * 256) >> 3;
            U8 uk, uv;
            uk.u = *reinterpret_cast<const u32x4*>(k + hb + (size_t)s * C_ + c8);
            uv.u = *reinterpret_cast<const u32x4*>(v + hb + (size_t)s * C_ + c8);
            #pragma unroll
            for (int jj = 0; jj < 8; jj++) {
                int w = jj ^ a;
                kT[(c8 + w) * 136 + s] = uk.h[w];
                vT[(c8 + w) * 136 + s] = uv.h[w];
            }
        }
        __syncthreads();
        #pragma unroll
        for (int ks = 0; ks < 4; ks++) {
            s16x8 fa[2], fb[2];
            #pragma unroll
            for (int ni = 0; ni < 2; ni++)
                fa[ni] = *reinterpret_cast<const s16x8*>(
                    &vT[(n0 + ni * 16 + r16) * 136 + ks * 32 + quad * 8]);
            #pragma unroll
            for (int mi = 0; mi < 2; mi++)
                fb[mi] = *reinterpret_cast<const s16x8*>(
                    &kT[(m0 + mi * 16 + r16) * 136 + ks * 32 + quad * 8]);
            #pragma unroll
            for (int ni = 0; ni < 2; ni++)
                #pragma unroll
                for (int mi = 0; mi < 2; mi++)
                    acc[ni][mi] = __builtin_amdgcn_mfma_f32_16x16x32_bf16(fa[ni], fb[mi], acc[ni][mi], 0, 0, 0);
        }
        __syncthreads();
    }
    float* out = S + (size_t)blk * (HS_ * HS_);
    #pragma unroll
    for (int ni = 0; ni < 2; ni++)
        #pragma unroll
        for (int mi = 0; mi < 2; mi++)
            #pragma unroll
            for (int i = 0; i < 4; i++)
                out[(n0 + ni * 16 + quad * 4 + i) * HS_ + m0 + mi * 16 + r16] = acc[ni][mi][i];
}

// ---------------- K3b: decay scan (elementwise in (n,m) layout) -------------
__global__ __launch_bounds__(256) void scan_kernel(
    const float* __restrict__ S, const float* __restrict__ td, u16* __restrict__ stT)
{
    int bh = blockIdx.x;
    int h = bh & (H_ - 1);
    float w = expf(-expf(td[h]));
    int tid = threadIdx.x;
    float st[16];
    #pragma unroll
    for (int i = 0; i < 16; i++) st[i] = 0.f;
    for (int c = 0; c < NC_; c++) {
        size_t off = ((size_t)(bh * NC_ + c)) * 4096 + tid * 16;
        const float* sp = S + off;
        #pragma unroll
        for (int i = 0; i < 16; i++) st[i] = w * (st[i] + sp[i]);
        U8 o0, o1;
        #pragma unroll
        for (int i = 0; i < 8; i++) { o0.h[i] = f2b(st[i]); o1.h[i] = f2b(st[8 + i]); }
        *reinterpret_cast<u32x4*>(stT + off)     = o0.u;
        *reinterpret_cast<u32x4*>(stT + off + 8) = o1.u;
    }
}

// ---------------- K3c: y = r @ state (MFMA), fused GroupNorm ----------------
__global__ __launch_bounds__(256) void rstate_gn_kernel(
    const u16* __restrict__ r, const u16* __restrict__ stT,
    const float* __restrict__ gnw, const float* __restrict__ gnb, u16* __restrict__ ygn)
{
    int blk = blockIdx.x;      // bh*NC + c
    int c  = blk & (NC_ - 1);
    int bh = blk >> 3;
    int h = bh & (H_ - 1);
    int b = bh >> 4;
    __shared__ __align__(16) u16 sT[HS_ * 72];   // pitch 72 u16
    int tid = threadIdx.x, lane = tid & 63, wave = tid >> 6;
    int r16 = lane & 15, quad = lane >> 4;

    const u16* sg = stT + (size_t)blk * (HS_ * HS_);
    for (int i = tid; i < 512; i += 256) {
        int n = i >> 3, c8 = (i & 7) * 8;
        *reinterpret_cast<u32x4*>(&sT[n * 72 + c8]) =
            *reinterpret_cast<const u32x4*>(sg + n * HS_ + c8);
    }
    __syncthreads();

    size_t rowBase = (size_t)(b * T_ + c * CHUNK_ + wave * 64);
    f32x4 acc[4][4];
    #pragma unroll
    for (int mi = 0; mi < 4; mi++)
        #pragma unroll
        for (int ni = 0; ni < 4; ni++)
            acc[mi][ni] = f32x4{0.f, 0.f, 0.f, 0.f};

    #pragma unroll
    for (int ks = 0; ks < 2; ks++) {
        int kb = ks * 32 + quad * 8;
        s16x8 fa[4], fb[4];
        #pragma unroll
        for (int mi = 0; mi < 4; mi++)
            fa[mi] = *reinterpret_cast<const s16x8*>(
                r + (rowBase + mi * 16 + r16) * C_ + h * HS_ + kb);
        #pragma unroll
        for (int ni = 0; ni < 4; ni++)
            fb[ni] = *reinterpret_cast<const s16x8*>(&sT[(ni * 16 + r16) * 72 + kb]);
        #pragma unroll
        for (int mi = 0; mi < 4; mi++)
            #pragma unroll
            for (int ni = 0; ni < 4; ni++)
                acc[mi][ni] = __builtin_amdgcn_mfma_f32_16x16x32_bf16(fa[mi], fb[ni], acc[mi][ni], 0, 0, 0);
    }

    float gwv[4], gbv[4];
    #pragma unroll
    for (int ni = 0; ni < 4; ni++) {
        int col = ni * 16 + r16;
        gwv[ni] = gnw[h * HS_ + col];
        gbv[ni] = gnb[h * HS_ + col];
    }
    #pragma unroll
    for (int mi = 0; mi < 4; mi++) {
        float s1[4], s2[4];
        #pragma unroll
        for (int i = 0; i < 4; i++) {
            float s = 0.f, ss = 0.f;
            #pragma unroll
            for (int ni = 0; ni < 4; ni++) {
                float v = acc[mi][ni][i];
                s += v; ss += v * v;
            }
            s1[i] = s; s2[i] = ss;
        }
        #pragma unroll
        for (int d = 1; d < 16; d <<= 1) {
            #pragma unroll
            for (int i = 0; i < 4; i++) {
                s1[i] += __shfl_xor(s1[i], d);
                s2[i] += __shfl_xor(s2[i], d);
            }
        }
        #pragma unroll
        for (int i = 0; i < 4; i++) {
            float mu = s1[i] * (1.f / 64.f);
            float var = s2[i] * (1.f / 64.f) - mu * mu;
            float sc = rsqrtf(var + 1e-5f);
            size_t ob = (rowBase + mi * 16 + quad * 4 + i) * C_ + h * HS_;
            #pragma unroll
            for (int ni = 0; ni < 4; ni++)
                ygn[ob + ni * 16 + r16] = f2b((acc[mi][ni][i] - mu) * sc * gwv[ni] + gbv[ni]);
        }
    }
}

// ---------------------------------------------------------------------------
extern "C" void kernel_launch(void* const* d_in, const int* in_sizes, int n_in,
                              void* d_out, int out_size, void* d_ws, size_t ws_size,
                              hipStream_t stream) {
    const float* x    = (const float*)d_in[0];
    const float* vol  = (const float*)d_in[1];
    const float* Wvol = (const float*)d_in[2];
    const float* bvol = (const float*)d_in[3];
    const float* mk   = (const float*)d_in[4];
    const float* mv   = (const float*)d_in[5];
    const float* mr   = (const float*)d_in[6];
    const float* td   = (const float*)d_in[7];
    const float* Wk   = (const float*)d_in[8];
    const float* Wv   = (const float*)d_in[9];
    const float* Wr   = (const float*)d_in[10];
    const float* Wo   = (const float*)d_in[11];
    const float* gnw  = (const float*)d_in[12];
    const float* gnb  = (const float*)d_in[13];
    float* out = (float*)d_out;

    // one-time: allow 128 KB dynamic LDS for the GEMM (host-side, capture-safe)
    static bool init_attr = []() {
        hipFuncSetAttribute(reinterpret_cast<const void*>(gemm_bt<false>),
                            hipFuncAttributeMaxDynamicSharedMemorySize, GEMM_LDS_BYTES);
        hipFuncSetAttribute(reinterpret_cast<const void*>(gemm_bt<true>),
                            hipFuncAttributeMaxDynamicSharedMemorySize, GEMM_LDS_BYTES);
        return true;
    }();
    (void)init_attr;

    char* ws = (char*)d_ws;
    const size_t SLOT = (size_t)B_ * T_ * C_ * 2;   // 33,554,432 B
    // s0: xr -> kb -> ygn ; s1: xk -> vb ; s2: xv -> S(f32) + stT(bf16) ; s3: rb
    u16* xr = (u16*)(ws + 0 * SLOT);
    u16* xk = (u16*)(ws + 1 * SLOT);
    u16* xv = (u16*)(ws + 2 * SLOT);
    u16* rb = (u16*)(ws + 3 * SLOT);
    u16* kb = (u16*)(ws + 0 * SLOT);
    u16* vb = (u16*)(ws + 1 * SLOT);
    float* S   = (float*)(ws + 2 * SLOT);                 // 16.8 MB
    u16*   stT = (u16*)  (ws + 2 * SLOT + SLOT / 2);      // 8.4 MB
    u16* ygn = (u16*)(ws + 0 * SLOT);
    u16* wtb = (u16*)(ws + 4 * SLOT);                     // 4 bf16 weight mats
    u16* wrb = wtb;
    u16* wkb = wrb + (size_t)C_ * C_;
    u16* wvb = wkb + (size_t)C_ * C_;
    u16* wob = wvb + (size_t)C_ * C_;

    cvt4_kernel<<<dim3(4 * (C_ * C_ / 8) / 256), dim3(256), 0, stream>>>(Wr, Wk, Wv, Wo, wtb);

    // B*(T/8)*(C/8) threads = 262144 -> 1024 blocks
    mix_kernel<<<dim3(1024), dim3(256), 0, stream>>>(
        x, vol, Wvol, bvol, mk, mv, mr, xk, xv, xr);

    // 64 bm-tiles x 4 bn-tiles; id = bn*64+bm so A-panel sharers co-XCD
    gemm_bt<false><<<dim3(256), dim3(512), GEMM_LDS_BYTES, stream>>>(xr, wrb, rb);
    gemm_bt<false><<<dim3(256), dim3(512), GEMM_LDS_BYTES, stream>>>(xk, wkb, kb);
    gemm_bt<false><<<dim3(256), dim3(512), GEMM_LDS_BYTES, stream>>>(xv, wvb, vb);

    kvouter_kernel<<<dim3(B_ * H_ * NC_), dim3(256), 0, stream>>>(kb, vb, S);
    scan_kernel<<<dim3(B_ * H_), dim3(256), 0, stream>>>(S, td, stT);
    rstate_gn_kernel<<<dim3(B_ * H_ * NC_), dim3(256), 0, stream>>>(rb, stT, gnw, gnb, ygn);

    gemm_bt<true><<<dim3(256), dim3(512), GEMM_LDS_BYTES, stream>>>(ygn, wob, out);
}

// Round 3
// 373.835 us; speedup vs baseline: 1.0870x; 1.0247x over previous
//
#include <hip/hip_runtime.h>

typedef unsigned short u16;
typedef __attribute__((ext_vector_type(4))) unsigned int u32x4;
typedef __attribute__((ext_vector_type(4))) float f32x4;
typedef __attribute__((ext_vector_type(8))) short s16x8;

#define B_ 8
#define T_ 2048
#define C_ 1024
#define H_ 16
#define HS_ 64
#define CHUNK_ 256
#define NC_ 8

union U8 { u32x4 u; u16 h[8]; };

__device__ __forceinline__ float b2f(u16 v) {
    union { unsigned int i; float f; } c; c.i = ((unsigned int)v) << 16; return c.f;
}
__device__ __forceinline__ u16 f2b(float f) {
    union { float f; unsigned int i; } c; c.f = f;
    unsigned int i = c.i;
    return (u16)((i + 0x7FFFu + ((i >> 16) & 1u)) >> 16);  // RNE
}
// fast sigmoid: v_exp_f32 + v_rcp_f32 (args here are tiny, ~0.02 — no range issues)
__device__ __forceinline__ float fsig(float z) {
    return __builtin_amdgcn_rcpf(1.f + __expf(-z));
}

// async 16B global->LDS (lds dest = wave-uniform base + lane*16)
typedef __attribute__((address_space(1))) void GV;
typedef __attribute__((address_space(3))) void LV;
__device__ __forceinline__ void glds16(const void* g, void* l) {
    __builtin_amdgcn_global_load_lds((GV*)g, (LV*)l, 16, 0, 0);
}

// ---------------- K0: f32 -> bf16 conversion of the 4 weight matrices ------
__global__ __launch_bounds__(256) void cvt4_kernel(
    const float* __restrict__ s0, const float* __restrict__ s1,
    const float* __restrict__ s2, const float* __restrict__ s3,
    u16* __restrict__ dst)
{
    int i = blockIdx.x * 256 + threadIdx.x;   // 4 * 131072 threads, 8 elems each
    int m = i >> 17;
    const float* s = (m == 0) ? s0 : (m == 1) ? s1 : (m == 2) ? s2 : s3;
    size_t j = (size_t)(i & 131071) * 8;
    f32x4 a = *reinterpret_cast<const f32x4*>(s + j);
    f32x4 b = *reinterpret_cast<const f32x4*>(s + j + 4);
    U8 o;
    #pragma unroll
    for (int k = 0; k < 4; k++) { o.h[k] = f2b(a[k]); o.h[4 + k] = f2b(b[k]); }
    *reinterpret_cast<u32x4*>(dst + (size_t)m * C_ * C_ + j) = o.u;
}

// ---------------- K1: gate + time-shift + maa mix, 8-row t-strip ------------
__global__ __launch_bounds__(256) void mix_kernel(
    const float* __restrict__ x, const float* __restrict__ vol,
    const float* __restrict__ Wvol, const float* __restrict__ bvol,
    const float* __restrict__ mk, const float* __restrict__ mv, const float* __restrict__ mr,
    u16* __restrict__ xk, u16* __restrict__ xv, u16* __restrict__ xr)
{
    int idx = blockIdx.x * 256 + threadIdx.x;      // B*(T/8)*(C/8) threads
    int c0 = (idx & 127) * 8;
    int bt8 = idx >> 7;
    int t0  = (bt8 & 255) * 8;
    int b   = bt8 >> 8;
    size_t rowOff = ((size_t)b * T_ + t0) * C_ + c0;

    float wv[8], bv[8], mkv[8], mvv[8], mrv[8];
    #pragma unroll
    for (int j = 0; j < 8; j += 4) {
        f32x4 a;
        a = *reinterpret_cast<const f32x4*>(Wvol + c0 + j);
        wv[j] = a[0]; wv[j+1] = a[1]; wv[j+2] = a[2]; wv[j+3] = a[3];
        a = *reinterpret_cast<const f32x4*>(bvol + c0 + j);
        bv[j] = a[0]; bv[j+1] = a[1]; bv[j+2] = a[2]; bv[j+3] = a[3];
        a = *reinterpret_cast<const f32x4*>(mk + c0 + j);
        mkv[j] = a[0]; mkv[j+1] = a[1]; mkv[j+2] = a[2]; mkv[j+3] = a[3];
        a = *reinterpret_cast<const f32x4*>(mv + c0 + j);
        mvv[j] = a[0]; mvv[j+1] = a[1]; mvv[j+2] = a[2]; mvv[j+3] = a[3];
        a = *reinterpret_cast<const f32x4*>(mr + c0 + j);
        mrv[j] = a[0]; mrv[j+1] = a[1]; mrv[j+2] = a[2]; mrv[j+3] = a[3];
    }

    const float* volb = vol + (size_t)b * T_;
    float gp[8];
    if (t0 == 0) {
        #pragma unroll
        for (int j = 0; j < 8; j++) gp[j] = 0.f;
    } else {
        float vp = volb[t0 - 1];
        #pragma unroll
        for (int j = 0; j < 8; j += 4) {
            f32x4 a = *reinterpret_cast<const f32x4*>(x + rowOff - C_ + j);
            gp[j]   = a[0] * fsig(vp * wv[j]   + bv[j]);
            gp[j+1] = a[1] * fsig(vp * wv[j+1] + bv[j+1]);
            gp[j+2] = a[2] * fsig(vp * wv[j+2] + bv[j+2]);
            gp[j+3] = a[3] * fsig(vp * wv[j+3] + bv[j+3]);
        }
    }

    #pragma unroll
    for (int s = 0; s < 8; s++) {
        float vc = volb[t0 + s];
        size_t off = rowOff + (size_t)s * C_;
        float g[8];
        #pragma unroll
        for (int j = 0; j < 8; j += 4) {
            f32x4 a = *reinterpret_cast<const f32x4*>(x + off + j);
            g[j]   = a[0] * fsig(vc * wv[j]   + bv[j]);
            g[j+1] = a[1] * fsig(vc * wv[j+1] + bv[j+1]);
            g[j+2] = a[2] * fsig(vc * wv[j+2] + bv[j+2]);
            g[j+3] = a[3] * fsig(vc * wv[j+3] + bv[j+3]);
        }
        U8 ok, ov, orr;
        #pragma unroll
        for (int j = 0; j < 8; j++) {
            float xx = gp[j] - g[j];
            ok.h[j]  = f2b(g[j] + xx * mkv[j]);
            ov.h[j]  = f2b(g[j] + xx * mvv[j]);
            orr.h[j] = f2b(g[j] + xx * mrv[j]);
            gp[j] = g[j];
        }
        *reinterpret_cast<u32x4*>(xk + off) = ok.u;
        *reinterpret_cast<u32x4*>(xv + off) = ov.u;
        *reinterpret_cast<u32x4*>(xr + off) = orr.u;
    }
}

// ---------------- K2: C = A @ W^T  (8-phase m201-style schedule) ------------
// 256x256 tile, BK=64, 8 waves (2M x 4N, each 128x64 out), 512 threads.
// LDS 128 KB = 2 buffers x {A 256x64, B 256x64} bf16. Per K-tile: 4 phases,
// each = {ds_read frag subtile | stage-issue} -> barrier -> lgkmcnt(0) ->
// setprio(1) 16xMFMA setprio(0) -> barrier. Stage quanta (A-half+B-half,
// 4 glds/thread) for tile t+1 issue at ph0/ph2 of tile t; single vmcnt(0)
// per tile at ph3 drains loads issued 2-4 phases earlier (~full-tile slack),
// never a zero-slack drain. Swizzle: LDS chunk c of row r holds global
// chunk c^(r&7) (16B chunks, 128B rows) — conflict-free ds_read_b128 and
// full-128B-line staging. XCD locality: bm = id&63 (A-panel sharers co-XCD).
#define GBM_ 256
#define GBN_ 256
#define GBK_ 64
#define GK_  1024
#define GNT_ 16                    // GK_/GBK_
#define GEMM_LDS_BYTES 131072      // 2 * (256*64 + 256*64) * 2B

template<bool F32OUT>
__global__ __launch_bounds__(512, 2) void gemm_bt(
    const u16* __restrict__ A, const u16* __restrict__ W, void* __restrict__ Cc)
{
    extern __shared__ __align__(16) u16 lds[];
    const int tid  = threadIdx.x;
    const int lane = tid & 63, w = tid >> 6;
    const int r16  = lane & 15, quad = lane >> 4;
    const int wm2  = w >> 2;         // 0..1 : M-half (128 rows)
    const int wn4  = w & 3;          // 0..3 : N-quarter (64 cols)
    const int id   = blockIdx.x;
    const int bm   = id & 63, bn = id >> 6;

    const u16* Ab = A + (size_t)bm * GBM_ * GK_;
    const u16* Wb = W + (size_t)bn * GBN_ * GK_;

    // stage source (pre-swizzled): wave w owns rows [w*16, w*16+16) of each
    // 128-row half; lane -> row_in_8 = lane>>3, global chunk = (lane&7)^(lane>>3)
    const int srow8  = lane >> 3;
    const int schunk = ((lane & 7) ^ srow8) * 8;            // elems
    const u16* aSrc = Ab + (size_t)(w * 16 + srow8) * GK_ + schunk;
    const u16* bSrc = Wb + (size_t)(w * 16 + srow8) * GK_ + schunk;

    // fragment read bases (u16 elems). LDS row pitch = 64 elems (128 B).
    const int fA0 = (wm2 * 128 + r16) * 64;
    const int fB0 = 16384 + (wn4 * 64 + r16) * 64;
    const int c0 = ((quad)     ^ (r16 & 7)) * 8;            // ks=0 chunk ofs
    const int c1 = ((quad | 4) ^ (r16 & 7)) * 8;            // ks=1 chunk ofs

    f32x4 acc[8][4];
    #pragma unroll
    for (int mi = 0; mi < 8; mi++)
        #pragma unroll
        for (int ni = 0; ni < 4; ni++)
            acc[mi][ni] = f32x4{0.f, 0.f, 0.f, 0.f};

#define STQ(tt, h) do {                                                       \
    const size_t ko_ = (size_t)(tt) * 64;                                     \
    u16* db_ = lds + (((tt) & 1) * 32768) + ((h) * 128 + w * 16) * 64;        \
    glds16(aSrc + (size_t)((h) * 128)     * GK_ + ko_, db_);                  \
    glds16(aSrc + (size_t)((h) * 128 + 8) * GK_ + ko_, db_ + 512);            \
    glds16(bSrc + (size_t)((h) * 128)     * GK_ + ko_, db_ + 16384);          \
    glds16(bSrc + (size_t)((h) * 128 + 8) * GK_ + ko_, db_ + 16384 + 512);    \
} while (0)

#define PH_BAR() do { asm volatile("" ::: "memory");                          \
    __builtin_amdgcn_s_barrier(); asm volatile("" ::: "memory"); } while (0)
#define PH_LGKM0() do { asm volatile("s_waitcnt lgkmcnt(0)" ::: "memory");    \
    __builtin_amdgcn_sched_barrier(0); } while (0)
#define LDFA(CO) { _Pragma("unroll") for (int mi = 0; mi < 8; mi++)           \
    fa[mi] = *reinterpret_cast<const s16x8*>(lds + pb + fA0 + mi * 1024 + (CO)); }
#define LDFB(NH, CO) { _Pragma("unroll") for (int ni = 0; ni < 2; ni++)       \
    fb[ni] = *reinterpret_cast<const s16x8*>(lds + pb + fB0 + ((NH) * 2 + ni) * 1024 + (CO)); }
#define MFMA16(NH) do { __builtin_amdgcn_s_setprio(1);                        \
    _Pragma("unroll") for (int mi = 0; mi < 8; mi++) {                        \
        acc[mi][(NH)*2+0] = __builtin_amdgcn_mfma_f32_16x16x32_bf16(          \
            fa[mi], fb[0], acc[mi][(NH)*2+0], 0, 0, 0);                       \
        acc[mi][(NH)*2+1] = __builtin_amdgcn_mfma_f32_16x16x32_bf16(          \
            fa[mi], fb[1], acc[mi][(NH)*2+1], 0, 0, 0);                       \
    } __builtin_amdgcn_s_setprio(0); } while (0)

    // prologue: stage both halves of tile 0, drain once, barrier
    STQ(0, 0);
    STQ(0, 1);
    asm volatile("s_waitcnt vmcnt(0)" ::: "memory");
    PH_BAR();

    for (int t = 0; t < GNT_; ++t) {
        const int pb = (t & 1) * 32768;
        s16x8 fa[8], fb[2];
        // ---- ph0: (ks0, nh0) — 10 reads + stage H0(t+1)
        LDFA(c0); LDFB(0, c0);
        if (t + 1 < GNT_) STQ(t + 1, 0);
        PH_BAR(); PH_LGKM0(); MFMA16(0); PH_BAR();
        // ---- ph1: (ks0, nh1) — 2 reads, reuse fa
        LDFB(1, c0);
        PH_BAR(); PH_LGKM0(); MFMA16(1); PH_BAR();
        // ---- ph2: (ks1, nh0) — 10 reads + stage H1(t+1)
        LDFA(c1); LDFB(0, c1);
        if (t + 1 < GNT_) STQ(t + 1, 1);
        PH_BAR(); PH_LGKM0(); MFMA16(0); PH_BAR();
        // ---- ph3: (ks1, nh1) — 2 reads; tile-end vmcnt(0) w/ ~full-tile slack
        LDFB(1, c1);
        PH_BAR(); PH_LGKM0(); MFMA16(1);
        asm volatile("s_waitcnt vmcnt(0)" ::: "memory");
        PH_BAR();
    }
#undef STQ
#undef LDFA
#undef LDFB
#undef MFMA16
#undef PH_LGKM0
#undef PH_BAR

    if constexpr (F32OUT) {
        // f32: 16 lanes * 4B = 64B full lines — direct store
        float* C = (float*)Cc;
        #pragma unroll
        for (int mi = 0; mi < 8; mi++) {
            int row0 = bm * GBM_ + wm2 * 128 + mi * 16 + quad * 4;
            #pragma unroll
            for (int ni = 0; ni < 4; ni++) {
                int col = bn * GBN_ + wn4 * 64 + ni * 16 + r16;
                #pragma unroll
                for (int i = 0; i < 4; i++)
                    C[(size_t)(row0 + i) * C_ + col] = acc[mi][ni][i];
            }
        }
    } else {
        // bf16: per-wave LDS patch [64][72] -> 128B-per-row dwordx4 stores
        // (final loop barrier above guarantees all buffer reads are done)
        u16* ep = lds + w * 4608;
        u16* C = (u16*)Cc;
        #pragma unroll
        for (int half = 0; half < 2; half++) {
            #pragma unroll
            for (int mi2 = 0; mi2 < 4; mi2++) {
                int mi = half * 4 + mi2;
                #pragma unroll
                for (int ni = 0; ni < 4; ni++)
                    #pragma unroll
                    for (int i = 0; i < 4; i++)
                        ep[(mi2 * 16 + quad * 4 + i) * 72 + ni * 16 + r16] =
                            f2b(acc[mi][ni][i]);
            }
            #pragma unroll
            for (int it = 0; it < 8; it++) {
                int rr = it * 8 + (lane >> 3);
                u32x4 val = *reinterpret_cast<const u32x4*>(ep + rr * 72 + (lane & 7) * 8);
                size_t grow = (size_t)(bm * GBM_ + wm2 * 128 + half * 64 + rr);
                *reinterpret_cast<u32x4*>(
                    C + grow * C_ + bn * GBN_ + wn4 * 64 + (lane & 7) * 8) = val;
            }
        }
    }
}

// ---------------- K3a: P = v^T k per (b,h,chunk) via MFMA -------------------
__global__ __launch_bounds__(256) void kvouter_kernel(
    const u16* __restrict__ k, const u16* __restrict__ v, float* __restrict__ S)
{
    int blk = blockIdx.x;          // bh*NC + j
    int j  = blk & (NC_ - 1);
    int bh = blk >> 3;
    int h = bh & (H_ - 1);
    int b = bh >> 4;
    __shared__ __align__(16) u16 kT[HS_ * 136];
    __shared__ __align__(16) u16 vT[HS_ * 136];
    int tid = threadIdx.x, lane = tid & 63, wave = tid >> 6;
    int r16 = lane & 15, quad = lane >> 4;
    int n0 = (wave >> 1) * 32, m0 = (wave & 1) * 32;
    int a = tid & 7, c8 = a * 8;

    f32x4 acc[2][2];
    #pragma unroll
    for (int ni = 0; ni < 2; ni++)
        #pragma unroll
        for (int mi = 0; mi < 2; mi++)
            acc[ni][mi] = f32x4{0.f, 0.f, 0.f, 0.f};

    size_t base = ((size_t)(b * T_ + j * CHUNK_)) * C_ + h * HS_;
    #pragma unroll
    for (int half = 0; half < 2; half++) {
        size_t hb = base + (size_t)half * 128 * C_;
        #pragma unroll
        for (int i = 0; i < 4; i++) {
            int s = (tid + i * 256) >> 3;
            U8 uk, uv;
            uk.u = *reinterpret_cast<const u32x4*>(k + hb + (size_t)s * C_ + c8);
            uv.u = *reinterpret_cast<const u32x4*>(v + hb + (size_t)s * C_ + c8);
            #pragma unroll
            for (int jj = 0; jj < 8; jj++) {
                int w = jj ^ a;
                kT[(c8 + w) * 136 + s] = uk.h[w];
                vT[(c8 + w) * 136 + s] = uv.h[w];
            }
        }
        __syncthreads();
        #pragma unroll
        for (int ks = 0; ks < 4; ks++) {
            s16x8 fa[2], fb[2];
            #pragma unroll
            for (int ni = 0; ni < 2; ni++)
                fa[ni] = *reinterpret_cast<const s16x8*>(
                    &vT[(n0 + ni * 16 + r16) * 136 + ks * 32 + quad * 8]);
            #pragma unroll
            for (int mi = 0; mi < 2; mi++)
                fb[mi] = *reinterpret_cast<const s16x8*>(
                    &kT[(m0 + mi * 16 + r16) * 136 + ks * 32 + quad * 8]);
            #pragma unroll
            for (int ni = 0; ni < 2; ni++)
                #pragma unroll
                for (int mi = 0; mi < 2; mi++)
                    acc[ni][mi] = __builtin_amdgcn_mfma_f32_16x16x32_bf16(fa[ni], fb[mi], acc[ni][mi], 0, 0, 0);
        }
        __syncthreads();
    }
    float* out = S + (size_t)blk * (HS_ * HS_);
    #pragma unroll
    for (int ni = 0; ni < 2; ni++)
        #pragma unroll
        for (int mi = 0; mi < 2; mi++)
            #pragma unroll
            for (int i = 0; i < 4; i++)
                out[(n0 + ni * 16 + quad * 4 + i) * HS_ + m0 + mi * 16 + r16] = acc[ni][mi][i];
}

// ---------------- K3b: decay scan (elementwise in (n,m) layout) -------------
__global__ __launch_bounds__(256) void scan_kernel(
    const float* __restrict__ S, const float* __restrict__ td, u16* __restrict__ stT)
{
    int bh = blockIdx.x;
    int h = bh & (H_ - 1);
    float w = expf(-expf(td[h]));
    int tid = threadIdx.x;
    float st[16];
    #pragma unroll
    for (int i = 0; i < 16; i++) st[i] = 0.f;
    for (int c = 0; c < NC_; c++) {
        size_t off = ((size_t)(bh * NC_ + c)) * 4096 + tid * 16;
        const float* sp = S + off;
        #pragma unroll
        for (int i = 0; i < 16; i++) st[i] = w * (st[i] + sp[i]);
        U8 o0, o1;
        #pragma unroll
        for (int i = 0; i < 8; i++) { o0.h[i] = f2b(st[i]); o1.h[i] = f2b(st[8 + i]); }
        *reinterpret_cast<u32x4*>(stT + off)     = o0.u;
        *reinterpret_cast<u32x4*>(stT + off + 8) = o1.u;
    }
}

// ---------------- K3c: y = r @ state (MFMA), fused GroupNorm ----------------
__global__ __launch_bounds__(256) void rstate_gn_kernel(
    const u16* __restrict__ r, const u16* __restrict__ stT,
    const float* __restrict__ gnw, const float* __restrict__ gnb, u16* __restrict__ ygn)
{
    int blk = blockIdx.x;      // bh*NC + c
    int c  = blk & (NC_ - 1);
    int bh = blk >> 3;
    int h = bh & (H_ - 1);
    int b = bh >> 4;
    __shared__ __align__(16) u16 sT[HS_ * 72];   // pitch 72 u16
    int tid = threadIdx.x, lane = tid & 63, wave = tid >> 6;
    int r16 = lane & 15, quad = lane >> 4;

    const u16* sg = stT + (size_t)blk * (HS_ * HS_);
    for (int i = tid; i < 512; i += 256) {
        int n = i >> 3, c8 = (i & 7) * 8;
        *reinterpret_cast<u32x4*>(&sT[n * 72 + c8]) =
            *reinterpret_cast<const u32x4*>(sg + n * HS_ + c8);
    }
    __syncthreads();

    size_t rowBase = (size_t)(b * T_ + c * CHUNK_ + wave * 64);
    f32x4 acc[4][4];
    #pragma unroll
    for (int mi = 0; mi < 4; mi++)
        #pragma unroll
        for (int ni = 0; ni < 4; ni++)
            acc[mi][ni] = f32x4{0.f, 0.f, 0.f, 0.f};

    #pragma unroll
    for (int ks = 0; ks < 2; ks++) {
        int kb = ks * 32 + quad * 8;
        s16x8 fa[4], fb[4];
        #pragma unroll
        for (int mi = 0; mi < 4; mi++)
            fa[mi] = *reinterpret_cast<const s16x8*>(
                r + (rowBase + mi * 16 + r16) * C_ + h * HS_ + kb);
        #pragma unroll
        for (int ni = 0; ni < 4; ni++)
            fb[ni] = *reinterpret_cast<const s16x8*>(&sT[(ni * 16 + r16) * 72 + kb]);
        #pragma unroll
        for (int mi = 0; mi < 4; mi++)
            #pragma unroll
            for (int ni = 0; ni < 4; ni++)
                acc[mi][ni] = __builtin_amdgcn_mfma_f32_16x16x32_bf16(fa[mi], fb[ni], acc[mi][ni], 0, 0, 0);
    }

    float gwv[4], gbv[4];
    #pragma unroll
    for (int ni = 0; ni < 4; ni++) {
        int col = ni * 16 + r16;
        gwv[ni] = gnw[h * HS_ + col];
        gbv[ni] = gnb[h * HS_ + col];
    }
    #pragma unroll
    for (int mi = 0; mi < 4; mi++) {
        float s1[4], s2[4];
        #pragma unroll
        for (int i = 0; i < 4; i++) {
            float s = 0.f, ss = 0.f;
            #pragma unroll
            for (int ni = 0; ni < 4; ni++) {
                float v = acc[mi][ni][i];
                s += v; ss += v * v;
            }
            s1[i] = s; s2[i] = ss;
        }
        #pragma unroll
        for (int d = 1; d < 16; d <<= 1) {
            #pragma unroll
            for (int i = 0; i < 4; i++) {
                s1[i] += __shfl_xor(s1[i], d);
                s2[i] += __shfl_xor(s2[i], d);
            }
        }
        #pragma unroll
        for (int i = 0; i < 4; i++) {
            float mu = s1[i] * (1.f / 64.f);
            float var = s2[i] * (1.f / 64.f) - mu * mu;
            float sc = rsqrtf(var + 1e-5f);
            size_t ob = (rowBase + mi * 16 + quad * 4 + i) * C_ + h * HS_;
            #pragma unroll
            for (int ni = 0; ni < 4; ni++)
                ygn[ob + ni * 16 + r16] = f2b((acc[mi][ni][i] - mu) * sc * gwv[ni] + gbv[ni]);
        }
    }
}

// ---------------------------------------------------------------------------
extern "C" void kernel_launch(void* const* d_in, const int* in_sizes, int n_in,
                              void* d_out, int out_size, void* d_ws, size_t ws_size,
                              hipStream_t stream) {
    const float* x    = (const float*)d_in[0];
    const float* vol  = (const float*)d_in[1];
    const float* Wvol = (const float*)d_in[2];
    const float* bvol = (const float*)d_in[3];
    const float* mk   = (const float*)d_in[4];
    const float* mv   = (const float*)d_in[5];
    const float* mr   = (const float*)d_in[6];
    const float* td   = (const float*)d_in[7];
    const float* Wk   = (const float*)d_in[8];
    const float* Wv   = (const float*)d_in[9];
    const float* Wr   = (const float*)d_in[10];
    const float* Wo   = (const float*)d_in[11];
    const float* gnw  = (const float*)d_in[12];
    const float* gnb  = (const float*)d_in[13];
    float* out = (float*)d_out;

    // one-time: allow 128 KB dynamic LDS for the GEMM (host-side, capture-safe)
    static bool init_attr = []() {
        hipFuncSetAttribute(reinterpret_cast<const void*>(gemm_bt<false>),
                            hipFuncAttributeMaxDynamicSharedMemorySize, GEMM_LDS_BYTES);
        hipFuncSetAttribute(reinterpret_cast<const void*>(gemm_bt<true>),
                            hipFuncAttributeMaxDynamicSharedMemorySize, GEMM_LDS_BYTES);
        return true;
    }();
    (void)init_attr;

    char* ws = (char*)d_ws;
    const size_t SLOT = (size_t)B_ * T_ * C_ * 2;   // 33,554,432 B
    // s0: xr -> kb -> ygn ; s1: xk -> vb ; s2: xv -> S(f32) + stT(bf16) ; s3: rb
    u16* xr = (u16*)(ws + 0 * SLOT);
    u16* xk = (u16*)(ws + 1 * SLOT);
    u16* xv = (u16*)(ws + 2 * SLOT);
    u16* rb = (u16*)(ws + 3 * SLOT);
    u16* kb = (u16*)(ws + 0 * SLOT);
    u16* vb = (u16*)(ws + 1 * SLOT);
    float* S   = (float*)(ws + 2 * SLOT);                 // 16.8 MB
    u16*   stT = (u16*)  (ws + 2 * SLOT + SLOT / 2);      // 8.4 MB
    u16* ygn = (u16*)(ws + 0 * SLOT);
    u16* wtb = (u16*)(ws + 4 * SLOT);                     // 4 bf16 weight mats
    u16* wrb = wtb;
    u16* wkb = wrb + (size_t)C_ * C_;
    u16* wvb = wkb + (size_t)C_ * C_;
    u16* wob = wvb + (size_t)C_ * C_;

    cvt4_kernel<<<dim3(4 * (C_ * C_ / 8) / 256), dim3(256), 0, stream>>>(Wr, Wk, Wv, Wo, wtb);

    // B*(T/8)*(C/8) threads = 262144 -> 1024 blocks
    mix_kernel<<<dim3(1024), dim3(256), 0, stream>>>(
        x, vol, Wvol, bvol, mk, mv, mr, xk, xv, xr);

    // 64 bm-tiles x 4 bn-tiles; id = bn*64+bm so A-panel sharers co-XCD
    gemm_bt<false><<<dim3(256), dim3(512), GEMM_LDS_BYTES, stream>>>(xr, wrb, rb);
    gemm_bt<false><<<dim3(256), dim3(512), GEMM_LDS_BYTES, stream>>>(xk, wkb, kb);
    gemm_bt<false><<<dim3(256), dim3(512), GEMM_LDS_BYTES, stream>>>(xv, wvb, vb);

    kvouter_kernel<<<dim3(B_ * H_ * NC_), dim3(256), 0, stream>>>(kb, vb, S);
    scan_kernel<<<dim3(B_ * H_), dim3(256), 0, stream>>>(S, td, stT);
    rstate_gn_kernel<<<dim3(B_ * H_ * NC_), dim3(256), 0, stream>>>(rb, stT, gnw, gnb, ygn);

    gemm_bt<true><<<dim3(256), dim3(512), GEMM_LDS_BYTES, stream>>>(ygn, wob, out);
}

// Round 4
// 339.445 us; speedup vs baseline: 1.1971x; 1.1013x over previous
//
#include <hip/hip_runtime.h>

typedef unsigned short u16;
typedef __attribute__((ext_vector_type(4))) unsigned int u32x4;
typedef __attribute__((ext_vector_type(4))) float f32x4;
typedef __attribute__((ext_vector_type(8))) short s16x8;

#define B_ 8
#define T_ 2048
#define C_ 1024
#define H_ 16
#define HS_ 64
#define CHUNK_ 256
#define NC_ 8

union U8 { u32x4 u; u16 h[8]; };

__device__ __forceinline__ float b2f(u16 v) {
    union { unsigned int i; float f; } c; c.i = ((unsigned int)v) << 16; return c.f;
}
__device__ __forceinline__ u16 f2b(float f) {
    union { float f; unsigned int i; } c; c.f = f;
    unsigned int i = c.i;
    return (u16)((i + 0x7FFFu + ((i >> 16) & 1u)) >> 16);  // RNE
}
// fast sigmoid: v_exp_f32 + v_rcp_f32 (args here are tiny, ~0.02 — no range issues)
__device__ __forceinline__ float fsig(float z) {
    return __builtin_amdgcn_rcpf(1.f + __expf(-z));
}

// async 16B global->LDS (lds dest = wave-uniform base + lane*16)
typedef __attribute__((address_space(1))) void GV;
typedef __attribute__((address_space(3))) void LV;
__device__ __forceinline__ void glds16(const void* g, void* l) {
    __builtin_amdgcn_global_load_lds((GV*)g, (LV*)l, 16, 0, 0);
}

// ---------------- K0: f32 -> bf16 conversion of the 4 weight matrices ------
__global__ __launch_bounds__(256) void cvt4_kernel(
    const float* __restrict__ s0, const float* __restrict__ s1,
    const float* __restrict__ s2, const float* __restrict__ s3,
    u16* __restrict__ dst)
{
    int i = blockIdx.x * 256 + threadIdx.x;   // 4 * 131072 threads, 8 elems each
    int m = i >> 17;
    const float* s = (m == 0) ? s0 : (m == 1) ? s1 : (m == 2) ? s2 : s3;
    size_t j = (size_t)(i & 131071) * 8;
    f32x4 a = *reinterpret_cast<const f32x4*>(s + j);
    f32x4 b = *reinterpret_cast<const f32x4*>(s + j + 4);
    U8 o;
    #pragma unroll
    for (int k = 0; k < 4; k++) { o.h[k] = f2b(a[k]); o.h[4 + k] = f2b(b[k]); }
    *reinterpret_cast<u32x4*>(dst + (size_t)m * C_ * C_ + j) = o.u;
}

// ---------------- K1: gate + time-shift + maa mix, 8-row t-strip ------------
__global__ __launch_bounds__(256) void mix_kernel(
    const float* __restrict__ x, const float* __restrict__ vol,
    const float* __restrict__ Wvol, const float* __restrict__ bvol,
    const float* __restrict__ mk, const float* __restrict__ mv, const float* __restrict__ mr,
    u16* __restrict__ xk, u16* __restrict__ xv, u16* __restrict__ xr)
{
    int idx = blockIdx.x * 256 + threadIdx.x;      // B*(T/8)*(C/8) threads
    int c0 = (idx & 127) * 8;
    int bt8 = idx >> 7;
    int t0  = (bt8 & 255) * 8;
    int b   = bt8 >> 8;
    size_t rowOff = ((size_t)b * T_ + t0) * C_ + c0;

    float wv[8], bv[8], mkv[8], mvv[8], mrv[8];
    #pragma unroll
    for (int j = 0; j < 8; j += 4) {
        f32x4 a;
        a = *reinterpret_cast<const f32x4*>(Wvol + c0 + j);
        wv[j] = a[0]; wv[j+1] = a[1]; wv[j+2] = a[2]; wv[j+3] = a[3];
        a = *reinterpret_cast<const f32x4*>(bvol + c0 + j);
        bv[j] = a[0]; bv[j+1] = a[1]; bv[j+2] = a[2]; bv[j+3] = a[3];
        a = *reinterpret_cast<const f32x4*>(mk + c0 + j);
        mkv[j] = a[0]; mkv[j+1] = a[1]; mkv[j+2] = a[2]; mkv[j+3] = a[3];
        a = *reinterpret_cast<const f32x4*>(mv + c0 + j);
        mvv[j] = a[0]; mvv[j+1] = a[1]; mvv[j+2] = a[2]; mvv[j+3] = a[3];
        a = *reinterpret_cast<const f32x4*>(mr + c0 + j);
        mrv[j] = a[0]; mrv[j+1] = a[1]; mrv[j+2] = a[2]; mrv[j+3] = a[3];
    }

    const float* volb = vol + (size_t)b * T_;
    float gp[8];
    if (t0 == 0) {
        #pragma unroll
        for (int j = 0; j < 8; j++) gp[j] = 0.f;
    } else {
        float vp = volb[t0 - 1];
        #pragma unroll
        for (int j = 0; j < 8; j += 4) {
            f32x4 a = *reinterpret_cast<const f32x4*>(x + rowOff - C_ + j);
            gp[j]   = a[0] * fsig(vp * wv[j]   + bv[j]);
            gp[j+1] = a[1] * fsig(vp * wv[j+1] + bv[j+1]);
            gp[j+2] = a[2] * fsig(vp * wv[j+2] + bv[j+2]);
            gp[j+3] = a[3] * fsig(vp * wv[j+3] + bv[j+3]);
        }
    }

    #pragma unroll
    for (int s = 0; s < 8; s++) {
        float vc = volb[t0 + s];
        size_t off = rowOff + (size_t)s * C_;
        float g[8];
        #pragma unroll
        for (int j = 0; j < 8; j += 4) {
            f32x4 a = *reinterpret_cast<const f32x4*>(x + off + j);
            g[j]   = a[0] * fsig(vc * wv[j]   + bv[j]);
            g[j+1] = a[1] * fsig(vc * wv[j+1] + bv[j+1]);
            g[j+2] = a[2] * fsig(vc * wv[j+2] + bv[j+2]);
            g[j+3] = a[3] * fsig(vc * wv[j+3] + bv[j+3]);
        }
        U8 ok, ov, orr;
        #pragma unroll
        for (int j = 0; j < 8; j++) {
            float xx = gp[j] - g[j];
            ok.h[j]  = f2b(g[j] + xx * mkv[j]);
            ov.h[j]  = f2b(g[j] + xx * mvv[j]);
            orr.h[j] = f2b(g[j] + xx * mrv[j]);
            gp[j] = g[j];
        }
        *reinterpret_cast<u32x4*>(xk + off) = ok.u;
        *reinterpret_cast<u32x4*>(xv + off) = ov.u;
        *reinterpret_cast<u32x4*>(xr + off) = orr.u;
    }
}

// ---------------- K2: C = A @ W^T  (8-phase schedule) -----------------------
// 256x256 tile, BK=64, 8 waves (2M x 4N), 512 threads, LDS 128 KB double-buf.
// MODE 0: f32 row-major out; MODE 1: bf16 row-major; MODE 2: bf16 TRANSPOSED
// out C^T[1024][16384] (for kvscan's s-contiguous fragment loads).
#define GBM_ 256
#define GBN_ 256
#define GBK_ 64
#define GK_  1024
#define GNT_ 16                    // GK_/GBK_
#define GEMM_LDS_BYTES 131072      // 2 * (256*64 + 256*64) * 2B

template<int MODE>
__global__ __launch_bounds__(512, 2) void gemm_bt(
    const u16* __restrict__ A, const u16* __restrict__ W, void* __restrict__ Cc)
{
    extern __shared__ __align__(16) u16 lds[];
    const int tid  = threadIdx.x;
    const int lane = tid & 63, w = tid >> 6;
    const int r16  = lane & 15, quad = lane >> 4;
    const int wm2  = w >> 2;         // 0..1 : M-half (128 rows)
    const int wn4  = w & 3;          // 0..3 : N-quarter (64 cols)
    const int id   = blockIdx.x;
    const int bm   = id & 63, bn = id >> 6;

    const u16* Ab = A + (size_t)bm * GBM_ * GK_;
    const u16* Wb = W + (size_t)bn * GBN_ * GK_;

    // stage source (pre-swizzled): wave w owns rows [w*16, w*16+16) of each
    // 128-row half; lane -> row_in_8 = lane>>3, global chunk = (lane&7)^(lane>>3)
    const int srow8  = lane >> 3;
    const int schunk = ((lane & 7) ^ srow8) * 8;            // elems
    const u16* aSrc = Ab + (size_t)(w * 16 + srow8) * GK_ + schunk;
    const u16* bSrc = Wb + (size_t)(w * 16 + srow8) * GK_ + schunk;

    // fragment read bases (u16 elems). LDS row pitch = 64 elems (128 B).
    const int fA0 = (wm2 * 128 + r16) * 64;
    const int fB0 = 16384 + (wn4 * 64 + r16) * 64;
    const int c0 = ((quad)     ^ (r16 & 7)) * 8;            // ks=0 chunk ofs
    const int c1 = ((quad | 4) ^ (r16 & 7)) * 8;            // ks=1 chunk ofs

    f32x4 acc[8][4];
    #pragma unroll
    for (int mi = 0; mi < 8; mi++)
        #pragma unroll
        for (int ni = 0; ni < 4; ni++)
            acc[mi][ni] = f32x4{0.f, 0.f, 0.f, 0.f};

#define STQ(tt, h) do {                                                       \
    const size_t ko_ = (size_t)(tt) * 64;                                     \
    u16* db_ = lds + (((tt) & 1) * 32768) + ((h) * 128 + w * 16) * 64;        \
    glds16(aSrc + (size_t)((h) * 128)     * GK_ + ko_, db_);                  \
    glds16(aSrc + (size_t)((h) * 128 + 8) * GK_ + ko_, db_ + 512);            \
    glds16(bSrc + (size_t)((h) * 128)     * GK_ + ko_, db_ + 16384);          \
    glds16(bSrc + (size_t)((h) * 128 + 8) * GK_ + ko_, db_ + 16384 + 512);    \
} while (0)

#define PH_BAR() do { asm volatile("" ::: "memory");                          \
    __builtin_amdgcn_s_barrier(); asm volatile("" ::: "memory"); } while (0)
#define PH_LGKM0() do { asm volatile("s_waitcnt lgkmcnt(0)" ::: "memory");    \
    __builtin_amdgcn_sched_barrier(0); } while (0)
#define LDFA(CO) { _Pragma("unroll") for (int mi = 0; mi < 8; mi++)           \
    fa[mi] = *reinterpret_cast<const s16x8*>(lds + pb + fA0 + mi * 1024 + (CO)); }
#define LDFB(NH, CO) { _Pragma("unroll") for (int ni = 0; ni < 2; ni++)       \
    fb[ni] = *reinterpret_cast<const s16x8*>(lds + pb + fB0 + ((NH) * 2 + ni) * 1024 + (CO)); }
#define MFMA16(NH) do { __builtin_amdgcn_s_setprio(1);                        \
    _Pragma("unroll") for (int mi = 0; mi < 8; mi++) {                        \
        acc[mi][(NH)*2+0] = __builtin_amdgcn_mfma_f32_16x16x32_bf16(          \
            fa[mi], fb[0], acc[mi][(NH)*2+0], 0, 0, 0);                       \
        acc[mi][(NH)*2+1] = __builtin_amdgcn_mfma_f32_16x16x32_bf16(          \
            fa[mi], fb[1], acc[mi][(NH)*2+1], 0, 0, 0);                       \
    } __builtin_amdgcn_s_setprio(0); } while (0)

    // prologue: stage both halves of tile 0, drain once, barrier
    STQ(0, 0);
    STQ(0, 1);
    asm volatile("s_waitcnt vmcnt(0)" ::: "memory");
    PH_BAR();

    for (int t = 0; t < GNT_; ++t) {
        const int pb = (t & 1) * 32768;
        s16x8 fa[8], fb[2];
        // ---- ph0: (ks0, nh0) — 10 reads + stage H0(t+1)
        LDFA(c0); LDFB(0, c0);
        if (t + 1 < GNT_) STQ(t + 1, 0);
        PH_BAR(); PH_LGKM0(); MFMA16(0); PH_BAR();
        // ---- ph1: (ks0, nh1) — 2 reads, reuse fa
        LDFB(1, c0);
        PH_BAR(); PH_LGKM0(); MFMA16(1); PH_BAR();
        // ---- ph2: (ks1, nh0) — 10 reads + stage H1(t+1)
        LDFA(c1); LDFB(0, c1);
        if (t + 1 < GNT_) STQ(t + 1, 1);
        PH_BAR(); PH_LGKM0(); MFMA16(0); PH_BAR();
        // ---- ph3: (ks1, nh1) — 2 reads; tile-end vmcnt(0) w/ ~full-tile slack
        LDFB(1, c1);
        PH_BAR(); PH_LGKM0(); MFMA16(1);
        asm volatile("s_waitcnt vmcnt(0)" ::: "memory");
        PH_BAR();
    }
#undef STQ
#undef LDFA
#undef LDFB
#undef MFMA16
#undef PH_LGKM0
#undef PH_BAR

    if constexpr (MODE == 0) {
        // f32: 16 lanes * 4B = 64B full lines — direct store
        float* C = (float*)Cc;
        #pragma unroll
        for (int mi = 0; mi < 8; mi++) {
            int row0 = bm * GBM_ + wm2 * 128 + mi * 16 + quad * 4;
            #pragma unroll
            for (int ni = 0; ni < 4; ni++) {
                int col = bn * GBN_ + wn4 * 64 + ni * 16 + r16;
                #pragma unroll
                for (int i = 0; i < 4; i++)
                    C[(size_t)(row0 + i) * C_ + col] = acc[mi][ni][i];
            }
        }
    } else if constexpr (MODE == 1) {
        // bf16 row-major: per-wave LDS patch [64][72] -> 128B-row dwordx4 stores
        u16* ep = lds + w * 4608;
        u16* C = (u16*)Cc;
        #pragma unroll
        for (int half = 0; half < 2; half++) {
            #pragma unroll
            for (int mi2 = 0; mi2 < 4; mi2++) {
                int mi = half * 4 + mi2;
                #pragma unroll
                for (int ni = 0; ni < 4; ni++)
                    #pragma unroll
                    for (int i = 0; i < 4; i++)
                        ep[(mi2 * 16 + quad * 4 + i) * 72 + ni * 16 + r16] =
                            f2b(acc[mi][ni][i]);
            }
            asm volatile("s_waitcnt lgkmcnt(0)" ::: "memory");
            __builtin_amdgcn_sched_barrier(0);
            #pragma unroll
            for (int it = 0; it < 8; it++) {
                int rr = it * 8 + (lane >> 3);
                u32x4 val = *reinterpret_cast<const u32x4*>(ep + rr * 72 + (lane & 7) * 8);
                size_t grow = (size_t)(bm * GBM_ + wm2 * 128 + half * 64 + rr);
                *reinterpret_cast<u32x4*>(
                    C + grow * C_ + bn * GBN_ + wn4 * 64 + (lane & 7) * 8) = val;
            }
            asm volatile("s_waitcnt vmcnt(0) lgkmcnt(0)" ::: "memory");
        }
    } else {
        // MODE 2: bf16 transposed C^T[1024][16384]. Per-wave LDS patch:
        // 64 local cols x 16 chunks(8 rows, 16B), chunk XOR-swizzled by col&15.
        u16* ep = lds + w * 8192;
        #pragma unroll
        for (int mi = 0; mi < 8; mi++) {
            const int chunk = mi * 2 + (quad >> 1);
            const int rsub = (quad & 1) * 4;
            #pragma unroll
            for (int ni = 0; ni < 4; ni++) {
                const int col = ni * 16 + r16;
                u16* p = ep + col * 128 + ((chunk ^ col) & 15) * 8 + rsub;
                p[0] = f2b(acc[mi][ni][0]);
                p[1] = f2b(acc[mi][ni][1]);
                p[2] = f2b(acc[mi][ni][2]);
                p[3] = f2b(acc[mi][ni][3]);
            }
        }
        asm volatile("s_waitcnt lgkmcnt(0)" ::: "memory");
        __builtin_amdgcn_sched_barrier(0);
        u16* C = (u16*)Cc;
        const int cl = lane >> 2, ch4 = lane & 3;
        #pragma unroll
        for (int it = 0; it < 16; it++) {
            const int col_l = (it & 3) * 16 + cl;
            const int chunk = (it >> 2) * 4 + ch4;
            u32x4 val = *reinterpret_cast<const u32x4*>(
                ep + col_l * 128 + ((chunk ^ col_l) & 15) * 8);
            const size_t gcol = (size_t)(bn * GBN_ + wn4 * 64 + col_l);
            const size_t grow = (size_t)(bm * GBM_ + wm2 * 128 + chunk * 8);
            *reinterpret_cast<u32x4*>(C + gcol * 16384 + grow) = val;
        }
    }
}

// ---------------- K3: fused P = v^T k  +  decay scan ------------------------
// Inputs are TRANSPOSED kT/vT [c][b*T+t] (t contiguous) so MFMA fragments
// (lane: 8 consecutive s at fixed channel) are direct 16B global loads —
// no LDS, no transpose, no barriers. One block per (b,h,m-half); running
// state held in registers across the 8 chunks; writes stT (bf16) directly.
__global__ __launch_bounds__(256) void kvscan_kernel(
    const u16* __restrict__ kT, const u16* __restrict__ vT,
    const float* __restrict__ td, u16* __restrict__ stT)
{
    const int bm2 = blockIdx.x;            // bh*2 + mh
    const int mh = bm2 & 1, bh = bm2 >> 1;
    const int h = bh & (H_ - 1), b = bh >> 4;
    const float wdec = expf(-expf(td[h]));
    const int tid = threadIdx.x, lane = tid & 63, wave = tid >> 6;
    const int r16 = lane & 15, quad = lane >> 4;
    const int n0 = wave * 16;              // wave owns 16 n-rows

    const size_t tb = (size_t)b * T_ + quad * 8;
    const u16* vr  = vT + (size_t)(h * HS_ + n0 + r16) * 16384 + tb;
    const u16* kr0 = kT + (size_t)(h * HS_ + mh * 32 + r16) * 16384 + tb;
    const u16* kr1 = kr0 + (size_t)16 * 16384;

    f32x4 st[2];
    st[0] = f32x4{0.f, 0.f, 0.f, 0.f};
    st[1] = f32x4{0.f, 0.f, 0.f, 0.f};

    for (int j = 0; j < NC_; j++) {
        f32x4 acc[2];
        acc[0] = f32x4{0.f, 0.f, 0.f, 0.f};
        acc[1] = f32x4{0.f, 0.f, 0.f, 0.f};
        const int jb = j * CHUNK_;
        #pragma unroll
        for (int ks = 0; ks < 8; ks++) {
            const int co = jb + ks * 32;
            s16x8 fa  = *reinterpret_cast<const s16x8*>(vr  + co);
            s16x8 fb0 = *reinterpret_cast<const s16x8*>(kr0 + co);
            s16x8 fb1 = *reinterpret_cast<const s16x8*>(kr1 + co);
            acc[0] = __builtin_amdgcn_mfma_f32_16x16x32_bf16(fa, fb0, acc[0], 0, 0, 0);
            acc[1] = __builtin_amdgcn_mfma_f32_16x16x32_bf16(fa, fb1, acc[1], 0, 0, 0);
        }
        u16* out = stT + ((size_t)bh * NC_ + j) * 4096;
        #pragma unroll
        for (int mi = 0; mi < 2; mi++) {
            st[mi] = (st[mi] + acc[mi]) * wdec;
            #pragma unroll
            for (int i = 0; i < 4; i++)
                out[(n0 + quad * 4 + i) * HS_ + mh * 32 + mi * 16 + r16] =
                    f2b(st[mi][i]);
        }
    }
}

// ---------------- K4: y = r @ state (MFMA), fused GroupNorm ----------------
__global__ __launch_bounds__(256) void rstate_gn_kernel(
    const u16* __restrict__ r, const u16* __restrict__ stT,
    const float* __restrict__ gnw, const float* __restrict__ gnb, u16* __restrict__ ygn)
{
    int blk = blockIdx.x;      // bh*NC + c
    int c  = blk & (NC_ - 1);
    int bh = blk >> 3;
    int h = bh & (H_ - 1);
    int b = bh >> 4;
    __shared__ __align__(16) u16 sT[HS_ * 72];   // pitch 72 u16
    int tid = threadIdx.x, lane = tid & 63, wave = tid >> 6;
    int r16 = lane & 15, quad = lane >> 4;

    const u16* sg = stT + (size_t)blk * (HS_ * HS_);
    for (int i = tid; i < 512; i += 256) {
        int n = i >> 3, c8 = (i & 7) * 8;
        *reinterpret_cast<u32x4*>(&sT[n * 72 + c8]) =
            *reinterpret_cast<const u32x4*>(sg + n * HS_ + c8);
    }
    __syncthreads();

    size_t rowBase = (size_t)(b * T_ + c * CHUNK_ + wave * 64);
    f32x4 acc[4][4];
    #pragma unroll
    for (int mi = 0; mi < 4; mi++)
        #pragma unroll
        for (int ni = 0; ni < 4; ni++)
            acc[mi][ni] = f32x4{0.f, 0.f, 0.f, 0.f};

    #pragma unroll
    for (int ks = 0; ks < 2; ks++) {
        int kb = ks * 32 + quad * 8;
        s16x8 fa[4], fb[4];
        #pragma unroll
        for (int mi = 0; mi < 4; mi++)
            fa[mi] = *reinterpret_cast<const s16x8*>(
                r + (rowBase + mi * 16 + r16) * C_ + h * HS_ + kb);
        #pragma unroll
        for (int ni = 0; ni < 4; ni++)
            fb[ni] = *reinterpret_cast<const s16x8*>(&sT[(ni * 16 + r16) * 72 + kb]);
        #pragma unroll
        for (int mi = 0; mi < 4; mi++)
            #pragma unroll
            for (int ni = 0; ni < 4; ni++)
                acc[mi][ni] = __builtin_amdgcn_mfma_f32_16x16x32_bf16(fa[mi], fb[ni], acc[mi][ni], 0, 0, 0);
    }

    float gwv[4], gbv[4];
    #pragma unroll
    for (int ni = 0; ni < 4; ni++) {
        int col = ni * 16 + r16;
        gwv[ni] = gnw[h * HS_ + col];
        gbv[ni] = gnb[h * HS_ + col];
    }
    #pragma unroll
    for (int mi = 0; mi < 4; mi++) {
        float s1[4], s2[4];
        #pragma unroll
        for (int i = 0; i < 4; i++) {
            float s = 0.f, ss = 0.f;
            #pragma unroll
            for (int ni = 0; ni < 4; ni++) {
                float v = acc[mi][ni][i];
                s += v; ss += v * v;
            }
            s1[i] = s; s2[i] = ss;
        }
        #pragma unroll
        for (int d = 1; d < 16; d <<= 1) {
            #pragma unroll
            for (int i = 0; i < 4; i++) {
                s1[i] += __shfl_xor(s1[i], d);
                s2[i] += __shfl_xor(s2[i], d);
            }
        }
        #pragma unroll
        for (int i = 0; i < 4; i++) {
            float mu = s1[i] * (1.f / 64.f);
            float var = s2[i] * (1.f / 64.f) - mu * mu;
            float sc = rsqrtf(var + 1e-5f);
            size_t ob = (rowBase + mi * 16 + quad * 4 + i) * C_ + h * HS_;
            #pragma unroll
            for (int ni = 0; ni < 4; ni++)
                ygn[ob + ni * 16 + r16] = f2b((acc[mi][ni][i] - mu) * sc * gwv[ni] + gbv[ni]);
        }
    }
}

// ---------------------------------------------------------------------------
extern "C" void kernel_launch(void* const* d_in, const int* in_sizes, int n_in,
                              void* d_out, int out_size, void* d_ws, size_t ws_size,
                              hipStream_t stream) {
    const float* x    = (const float*)d_in[0];
    const float* vol  = (const float*)d_in[1];
    const float* Wvol = (const float*)d_in[2];
    const float* bvol = (const float*)d_in[3];
    const float* mk   = (const float*)d_in[4];
    const float* mv   = (const float*)d_in[5];
    const float* mr   = (const float*)d_in[6];
    const float* td   = (const float*)d_in[7];
    const float* Wk   = (const float*)d_in[8];
    const float* Wv   = (const float*)d_in[9];
    const float* Wr   = (const float*)d_in[10];
    const float* Wo   = (const float*)d_in[11];
    const float* gnw  = (const float*)d_in[12];
    const float* gnb  = (const float*)d_in[13];
    float* out = (float*)d_out;

    // one-time: allow 128 KB dynamic LDS for the GEMM (host-side, capture-safe)
    static bool init_attr = []() {
        hipFuncSetAttribute(reinterpret_cast<const void*>(gemm_bt<0>),
                            hipFuncAttributeMaxDynamicSharedMemorySize, GEMM_LDS_BYTES);
        hipFuncSetAttribute(reinterpret_cast<const void*>(gemm_bt<1>),
                            hipFuncAttributeMaxDynamicSharedMemorySize, GEMM_LDS_BYTES);
        hipFuncSetAttribute(reinterpret_cast<const void*>(gemm_bt<2>),
                            hipFuncAttributeMaxDynamicSharedMemorySize, GEMM_LDS_BYTES);
        return true;
    }();
    (void)init_attr;

    char* ws = (char*)d_ws;
    const size_t SLOT = (size_t)B_ * T_ * C_ * 2;   // 33,554,432 B
    // s0: xr -> kbT -> ygn ; s1: xk -> vbT ; s2: xv -> stT ; s3: rb
    u16* xr = (u16*)(ws + 0 * SLOT);
    u16* xk = (u16*)(ws + 1 * SLOT);
    u16* xv = (u16*)(ws + 2 * SLOT);
    u16* rb = (u16*)(ws + 3 * SLOT);
    u16* kbT = (u16*)(ws + 0 * SLOT);                    // [1024][16384]
    u16* vbT = (u16*)(ws + 1 * SLOT);                    // [1024][16384]
    u16* stT = (u16*)(ws + 2 * SLOT + SLOT / 2);         // 8.4 MB
    u16* ygn = (u16*)(ws + 0 * SLOT);
    u16* wtb = (u16*)(ws + 4 * SLOT);                    // 4 bf16 weight mats
    u16* wrb = wtb;
    u16* wkb = wrb + (size_t)C_ * C_;
    u16* wvb = wkb + (size_t)C_ * C_;
    u16* wob = wvb + (size_t)C_ * C_;

    cvt4_kernel<<<dim3(4 * (C_ * C_ / 8) / 256), dim3(256), 0, stream>>>(Wr, Wk, Wv, Wo, wtb);

    // B*(T/8)*(C/8) threads = 262144 -> 1024 blocks
    mix_kernel<<<dim3(1024), dim3(256), 0, stream>>>(
        x, vol, Wvol, bvol, mk, mv, mr, xk, xv, xr);

    // 64 bm-tiles x 4 bn-tiles; id = bn*64+bm so A-panel sharers co-XCD
    gemm_bt<1><<<dim3(256), dim3(512), GEMM_LDS_BYTES, stream>>>(xr, wrb, rb);
    gemm_bt<2><<<dim3(256), dim3(512), GEMM_LDS_BYTES, stream>>>(xk, wkb, kbT);
    gemm_bt<2><<<dim3(256), dim3(512), GEMM_LDS_BYTES, stream>>>(xv, wvb, vbT);

    // fused kv-outer + decay scan: 256 blocks (b,h,m-half)
    kvscan_kernel<<<dim3(B_ * H_ * 2), dim3(256), 0, stream>>>(kbT, vbT, td, stT);

    rstate_gn_kernel<<<dim3(B_ * H_ * NC_), dim3(256), 0, stream>>>(rb, stT, gnw, gnb, ygn);

    gemm_bt<0><<<dim3(256), dim3(512), GEMM_LDS_BYTES, stream>>>(ygn, wob, out);
}